// Round 2
// baseline (14116.599 us; speedup 1.0000x reference)
//
#include <hip/hip_runtime.h>
#include <hip/hip_fp16.h>

// TKANCell B=64,T=2048,D=128,U=128,NS=3 — fp32 in/out.
// 64 independent chains (tf.reshape routes sub-row r=3b'+j to batch b'=r/3).
// R7: R6 counters showed tkan2 latency-bound (VALUBusy 11.8%, HBM 0.2%,
// 13440 cyc/step): Wr/Aw L2 re-streams + per-step gax HBM load + 6 barriers.
// Fix: (1) Wr+Aw fp16 register-resident via union array wreg[64] (threads
// 0-191 hold Wr cols, 192-447 hold Aw cols; loaded once pre-loop);
// (2) gax staged to LDS in 8-step chunks (HBM latency amortized 8x);
// (3) S1+S1r and S2+S2r merged via __shfl_xor(32) K-split reduce (6->4
// barriers, part1/part2 deleted). Accumulation order preserved except S3
// final regroup (fp32 reassoc noise only).

#define TT 2048
#define BB 64
#define TC 32

typedef unsigned int u32;

__device__ __forceinline__ float sigf(float x) { return 1.f / (1.f + __expf(-x)); }
__device__ __forceinline__ float tanh_(float x) { return 2.f / (1.f + __expf(-2.f * x)) - 1.f; }
__device__ __forceinline__ float2 h2f2(u32 u) {
    __half2 h = *(__half2*)&u;
    return __half22float2(h);
}

__device__ __forceinline__ void fma4(float4& acc, uint2 w, float xv) {
    float2 lo = h2f2(w.x), hi = h2f2(w.y);
    acc.x += lo.x * xv; acc.y += lo.y * xv;
    acc.z += hi.x * xv; acc.w += hi.y * xv;
}

// register-array dot: acc += Wcols[k] * v[k], k in [0,KN); v 16B-aligned LDS.
template <int KN>
__device__ __forceinline__ void dot_reg(const uint2* wr, const float* __restrict__ v,
                                        float4& acc) {
#pragma unroll
    for (int k = 0; k < KN; k += 4) {
        float4 vv = *(const float4*)&v[k];
        fma4(acc, wr[k + 0], vv.x);
        fma4(acc, wr[k + 1], vv.y);
        fma4(acc, wr[k + 2], vv.z);
        fma4(acc, wr[k + 3], vv.w);
    }
}

// LDS weight dot: acc += Wp[k*stride] * v[k], k in [0,KN).
template <int KN>
__device__ __forceinline__ void dot_ldsW(const uint2* Wp, int stride,
                                         const float* __restrict__ v, float4& acc) {
#pragma unroll
    for (int k = 0; k < KN; k += 4) {
        float4 vv = *(const float4*)&v[k];
        fma4(acc, Wp[(k + 0) * stride], vv.x);
        fma4(acc, Wp[(k + 1) * stride], vv.y);
        fma4(acc, Wp[(k + 2) * stride], vv.z);
        fma4(acc, Wp[(k + 3) * stride], vv.w);
    }
}

// legacy dot for fallback kernel
template <bool WS>
__device__ __forceinline__ void dotq(const void* W, int idxBase, int stride,
                                     const float* __restrict__ v, int k0, int kn,
                                     float4& acc) {
    if (WS) {
        const uint2* Wp = (const uint2*)W;
#pragma unroll 8
        for (int k = k0; k < k0 + kn; ++k) {
            uint2 w = Wp[idxBase + k * stride];
            float2 lo = h2f2(w.x), hi = h2f2(w.y);
            float xv = v[k];
            acc.x += lo.x * xv; acc.y += lo.y * xv;
            acc.z += hi.x * xv; acc.w += hi.y * xv;
        }
    } else {
        const float4* Wp = (const float4*)W;
#pragma unroll 8
        for (int k = k0; k < k0 + kn; ++k) {
            float4 w = Wp[idxBase + k * stride];
            float xv = v[k];
            acc.x += w.x * xv; acc.y += w.y * xv;
            acc.z += w.z * xv; acc.w += w.w * xv;
        }
    }
}

// fp16 copy of Wr|Wh|Dw|Aw (each 49152 elems, layout preserved).
__global__ __launch_bounds__(512) void convert_w(
    const float* __restrict__ Wr, const float* __restrict__ Wh,
    const float* __restrict__ Dw, const float* __restrict__ Aw,
    __half* __restrict__ dst) {
    int g = blockIdx.x * 512 + threadIdx.x;  // 0..196607
    int seg = g / 49152, idx = g % 49152;
    const float* src = (seg == 0) ? Wr : (seg == 1) ? Wh : (seg == 2) ? Dw : Aw;
    dst[g] = __float2half(src[idx]);
}

// ===== pre-pass: gax[bp][t][768] fp16 = [x@Wk (384) | x@Wx slices (384)].
__global__ __launch_bounds__(384, 3) void gax_pre(
    const float* __restrict__ xg, const float* __restrict__ Wk,
    const float* __restrict__ Wx, __half* __restrict__ gax) {
    const int bp = blockIdx.x, tc = blockIdx.y, tid = threadIdx.x;
    const int t0 = tc * 32;
    __shared__ __align__(16) float xCt[4][128][32];  // 64KB, [v][k][ti]

    for (int f = tid; f < 4096; f += 384) {
        int v_ = f >> 10, ti = (f >> 5) & 31, kq = f & 31;
        int row = (v_ == 0) ? bp : ((3 * bp + (v_ - 1)) & 63);
        float4 w = ((const float4*)(xg + ((size_t)row * TT + t0 + ti) * 128))[kq];
        xCt[v_][4 * kq + 0][ti] = w.x;
        xCt[v_][4 * kq + 1][ti] = w.y;
        xCt[v_][4 * kq + 2][ti] = w.z;
        xCt[v_][4 * kq + 3][ti] = w.w;
    }
    __syncthreads();

    const float4* Wk4 = (const float4*)Wk;
    const float4* Wx4 = (const float4*)Wx;

    for (int task = tid; task < 768; task += 384) {
        int grp = task / 192, r = task % 192;
        int ti0 = grp * 8;
        const float4* Wp;
        int base, stride, v;
        if (r < 96) {
            Wp = Wk4; base = r; stride = 96; v = 0;
        } else {
            int jq = r - 96, j = jq >> 5, qi = jq & 31;
            int nj = (3 * bp + j) >> 6;
            Wp = Wx4; base = nj * 4096 + qi; stride = 32; v = 1 + j;
        }
        float4 acc[8];
#pragma unroll
        for (int i = 0; i < 8; ++i) acc[i] = make_float4(0.f, 0.f, 0.f, 0.f);
#pragma unroll 4
        for (int k = 0; k < 128; ++k) {
            float4 w = Wp[base + k * stride];
            float4 xa = *(const float4*)&xCt[v][k][ti0];
            float4 xb = *(const float4*)&xCt[v][k][ti0 + 4];
#pragma unroll
            for (int i = 0; i < 4; ++i) {
                float xv = (&xa.x)[i];
                acc[i].x += w.x * xv; acc[i].y += w.y * xv;
                acc[i].z += w.z * xv; acc[i].w += w.w * xv;
            }
#pragma unroll
            for (int i = 0; i < 4; ++i) {
                float xv = (&xb.x)[i];
                acc[4 + i].x += w.x * xv; acc[4 + i].y += w.y * xv;
                acc[4 + i].z += w.z * xv; acc[4 + i].w += w.w * xv;
            }
        }
#pragma unroll
        for (int i = 0; i < 8; ++i) {
            size_t off = ((size_t)bp * TT + (size_t)(t0 + ti0 + i)) * 768 + 4 * r;
            __half2 lo = __floats2half2_rn(acc[i].x, acc[i].y);
            __half2 hi = __floats2half2_rn(acc[i].z, acc[i].w);
            uint2 pk = make_uint2(*(u32*)&lo, *(u32*)&hi);
            *(uint2*)(gax + off) = pk;
        }
    }
}

// ===== R7 serial kernel: Wr/Aw in registers, Wh/Dw in LDS, gax 8-step LDS
// chunks, 4 barriers/step via in-wave shfl K-reduction.
__global__ __launch_bounds__(512, 1) void tkan3(
    const float* __restrict__ bias, const float* __restrict__ stk,
    const float* __restrict__ Db, const float* __restrict__ Ab,
    const __half* __restrict__ wt, float* __restrict__ outp) {
    const int bp = blockIdx.x, tid = threadIdx.x;
    const int w = tid >> 6, l = tid & 63, qq = l & 31, ks = l >> 5;

    __shared__ uint2 WhL[8192];               // up to 2 slices (64KB)
    __shared__ uint2 DwL[8192];               // 64KB
    __shared__ __align__(16) uint2 gxS[1536]; // 8 steps x 192 uint2 (12KB)
    __shared__ __align__(16) float hS[128], cS[128], tcS[128];
    __shared__ __align__(16) float sS[384], aS[384], pS[384], gS[384];
    __shared__ __align__(16) float part3[4][32][4];
    __shared__ float biasL[384], stkj[3][2][128], DbL[3][128], AbL[128];

    const int nj0 = (3 * bp) >> 6;
    const int nslice = ((3 * bp + 2) >> 6) - nj0 + 1;  // 1 or 2

    if (tid < 128) { hS[tid] = 0.f; cS[tid] = 0.f; AbL[tid] = Ab[tid]; }
    if (tid >= 128 && tid < 512) {
        int q = tid - 128;
        sS[q] = 0.f;
        biasL[q] = bias[q];
    }
    {
        int j = tid >> 7, o = tid & 127;
        if (j < 3) {
            int nj = (3 * bp + j) >> 6;
            stkj[j][0][o] = stk[nj * 256 + o];
            stkj[j][1][o] = stk[nj * 256 + 128 + o];
            DbL[j][o] = Db[nj * 128 + o];
        }
    }
    const uint2* wtWr = (const uint2*)wt;
    const uint2* wtWh = (const uint2*)(wt + 49152);
    const uint2* wtDw = (const uint2*)(wt + 98304);
    const uint2* wtAw = (const uint2*)(wt + 147456);
    for (int i = tid; i < nslice * 4096; i += 512) {
        int s = i >> 12, idx = i & 4095;
        WhL[i] = wtWh[(nj0 + s) * 4096 + idx];
        DwL[i] = wtDw[(nj0 + s) * 4096 + idx];
    }

    // ---- register-resident weight columns (union: Wr for tid<192, Aw for
    // tid in [192,448)). 64 uint2 = 128 VGPRs.
    uint2 wreg[64];
    if (tid < 192) {
        int q = 32 * w + qq;  // Wr quad, K-half ks
#pragma unroll
        for (int i = 0; i < 64; ++i) wreg[i] = wtWr[q + (64 * ks + i) * 96];
    } else if (tid < 448) {
        int idx = tid - 192, q = idx & 31, ks8 = idx >> 5;  // Aw quad, K/8
#pragma unroll
        for (int i = 0; i < 48; ++i) wreg[i] = wtAw[q + (48 * ks8 + i) * 32];
    }
    __syncthreads();

    const uint2* gaxRow = (const uint2*)(wt + 196608 + (size_t)bp * TT * 768);

    for (int t = 0; t < TT; ++t) {
        if ((t & 7) == 0) {
            // stage 8 steps of gax (768 uint4) into LDS
            const uint4* g4 = (const uint4*)(gaxRow + (size_t)t * 192);
            for (int i = tid; i < 768; i += 512) ((uint4*)gxS)[i] = g4[i];
            __syncthreads();
        }

        // ===== S1: gates (Wr, registers) + agg-in (Wh, LDS); K split across
        // half-waves, reduced via shfl_xor(32); lane<32 adds gax(+bias).
        if (tid < 384) {
            float4 acc = {0.f, 0.f, 0.f, 0.f};
            if (w < 3) {
                dot_reg<64>(wreg, hS + 64 * ks, acc);
            } else {
                int j = w - 3;
                int sj = ((3 * bp + j) >> 6) - nj0;
                dot_ldsW<64>(WhL + sj * 4096 + qq + (64 * ks) * 32, 32,
                             sS + j * 128 + 64 * ks, acc);
            }
            acc.x += __shfl_xor(acc.x, 32, 64);
            acc.y += __shfl_xor(acc.y, 32, 64);
            acc.z += __shfl_xor(acc.z, 32, 64);
            acc.w += __shfl_xor(acc.w, 32, 64);
            if (l < 32) {
                uint2 gv = gxS[(t & 7) * 192 + 32 * w + qq];
                float2 g0 = h2f2(gv.x), g1 = h2f2(gv.y);
                if (w < 3) {
                    int q = 32 * w + qq;
                    float4 r;
                    r.x = acc.x + g0.x + biasL[4 * q];
                    r.y = acc.y + g0.y + biasL[4 * q + 1];
                    r.z = acc.z + g1.x + biasL[4 * q + 2];
                    r.w = acc.w + g1.y + biasL[4 * q + 3];
                    *(float4*)&gS[4 * q] = r;
                } else {
                    int cq = 32 * (w - 3) + qq;
                    float4 r;
                    r.x = acc.x + g0.x;
                    r.y = acc.y + g0.y;
                    r.z = acc.z + g1.x;
                    r.w = acc.w + g1.y;
                    *(float4*)&aS[4 * cq] = r;
                }
            }
        }
        __syncthreads();

        // ===== S2: sub-dense (Dw, LDS) with shfl reduce -> pS; c-update on
        // threads 384+ in parallel.
        if (tid < 192) {
            int j = w;  // 0..2
            int sj = ((3 * bp + j) >> 6) - nj0;
            float4 acc = {0.f, 0.f, 0.f, 0.f};
            dot_ldsW<64>(DwL + sj * 4096 + qq + (64 * ks) * 32, 32,
                         aS + j * 128 + 64 * ks, acc);
            acc.x += __shfl_xor(acc.x, 32, 64);
            acc.y += __shfl_xor(acc.y, 32, 64);
            acc.z += __shfl_xor(acc.z, 32, 64);
            acc.w += __shfl_xor(acc.w, 32, 64);
            if (l < 32) {
                int o = 4 * qq;
                float4 r;
                r.x = fmaxf(acc.x + DbL[j][o], 0.f);
                r.y = fmaxf(acc.y + DbL[j][o + 1], 0.f);
                r.z = fmaxf(acc.z + DbL[j][o + 2], 0.f);
                r.w = fmaxf(acc.w + DbL[j][o + 3], 0.f);
                *(float4*)&pS[j * 128 + o] = r;
            }
        } else if (tid >= 384) {
            int u = tid - 384;
            float gi = sigf(gS[u]);
            float gf = sigf(gS[128 + u]);
            float gc = sigf(gS[256 + u]);
            float cn = gf * cS[u] + gi * tanh_(gc);
            cS[u] = cn;
            tcS[u] = tanh_(cn);
        }
        __syncthreads();

        // ===== S3: aggregate (Aw, registers, K/8 x shfl-pair) ; s-update.
        if (tid >= 192 && tid < 448) {
            int idx = tid - 192, q = idx & 31, ks8 = idx >> 5;
            float4 acc = {0.f, 0.f, 0.f, 0.f};
            dot_reg<48>(wreg, pS + 48 * ks8, acc);
            acc.x += __shfl_xor(acc.x, 32, 64);
            acc.y += __shfl_xor(acc.y, 32, 64);
            acc.z += __shfl_xor(acc.z, 32, 64);
            acc.w += __shfl_xor(acc.w, 32, 64);
            if (l < 32) *(float4*)&part3[w - 3][q][0] = acc;
        } else if (tid < 128) {
            int e = tid;
#pragma unroll
            for (int j = 0; j < 3; ++j) {
                int q = j * 128 + e;
                sS[q] = stkj[j][0][e] * pS[q] + stkj[j][1][e] * sS[q];
            }
        }
        __syncthreads();

        // ===== S3r: finalize h, write out
        if (tid < 128) {
            int u = tid;
            float y = AbL[u];
#pragma unroll
            for (int p = 0; p < 4; ++p) y += part3[p][u >> 2][u & 3];
            float hn = sigf(y) * tcS[u];
            hS[u] = hn;
            outp[((size_t)bp * TT + t) * 128 + u] = hn;
        }
        __syncthreads();
    }
}

// ===== Verified fallback (unchanged): chunk-phase kernel =====
template <bool WS>
__global__ __launch_bounds__(512, 1) void tkan(
    const float* __restrict__ xg, const float* __restrict__ Wk,
    const float* __restrict__ Wr, const float* __restrict__ bias,
    const float* __restrict__ Wx, const float* __restrict__ Wh,
    const float* __restrict__ stk, const float* __restrict__ Dw,
    const float* __restrict__ Db, const float* __restrict__ Aw,
    const float* __restrict__ Ab, const __half* __restrict__ wt,
    float* __restrict__ outp) {
    const int bp = blockIdx.x, tid = threadIdx.x;

    __shared__ float xC[4][TC][128];
    __shared__ __half gxL[TC][384];
    __shared__ __half axL[TC][384];
    __shared__ float hS[128], cS[128], tcS[128];
    __shared__ float sS[384], aS[384], pS[384], gS[384];
    __shared__ float part1[384][4], part2[192][4], part3[256][4];
    __shared__ float biasL[384], stkj[3][2][128], DbL[3][128], AbL[128];
    __shared__ float dummy[WS ? 4 : 4096];

    if (tid < 128) { hS[tid] = 0.f; cS[tid] = 0.f; AbL[tid] = Ab[tid]; }
    if (tid >= 128 && tid < 512) {
        int q = tid - 128;
        sS[q] = 0.f;
        biasL[q] = bias[q];
    }
    {
        int j = tid >> 7, o = tid & 127;
        if (j < 3) {
            int nj = (3 * bp + j) >> 6;
            stkj[j][0][o] = stk[nj * 256 + o];
            stkj[j][1][o] = stk[nj * 256 + 128 + o];
            DbL[j][o] = Db[nj * 128 + o];
        }
    }
    if (bias[0] > 1e30f) { dummy[tid & 3] = 1.f; }
    __syncthreads();

    const float4* Wk4 = (const float4*)Wk;
    const float4* Wx4 = (const float4*)Wx;
    const void* wWr = WS ? (const void*)(wt)          : (const void*)Wr;
    const void* wWh = WS ? (const void*)(wt + 49152)  : (const void*)Wh;
    const void* wDw = WS ? (const void*)(wt + 98304)  : (const void*)Dw;
    const void* wAw = WS ? (const void*)(wt + 147456) : (const void*)Aw;

    for (int t = 0; t < TT; ++t) {
        int tt = t & (TC - 1);
        if (tt == 0) {
            for (int f = tid; f < 4096; f += 512) {
                int v_ = f >> 10, ti = (f >> 5) & 31, kq = f & 31;
                int row = (v_ == 0) ? bp : ((3 * bp + (v_ - 1)) & 63);
                float4 w = ((const float4*)(xg + ((size_t)row * TT + t + ti) * 128))[kq];
                float* d = &xC[v_][ti][kq * 4];
                d[0] = w.x; d[1] = w.y; d[2] = w.z; d[3] = w.w;
            }
            __syncthreads();
            for (int ct = tid; ct < TC * 192; ct += 512) {
                int ti = ct / 192, r = ct % 192;
                float4 acc = {0.f, 0.f, 0.f, 0.f};
                if (r < 96) {
                    const float* v = xC[0][ti];
#pragma unroll 8
                    for (int k = 0; k < 128; ++k) {
                        float4 w = Wk4[k * 96 + r];
                        float xv = v[k];
                        acc.x += w.x * xv; acc.y += w.y * xv;
                        acc.z += w.z * xv; acc.w += w.w * xv;
                    }
                    int qout = r;
                    ((__half2*)&gxL[ti][0])[2 * qout] = __floats2half2_rn(acc.x, acc.y);
                    ((__half2*)&gxL[ti][0])[2 * qout + 1] = __floats2half2_rn(acc.z, acc.w);
                } else {
                    int jq = r - 96, j = jq >> 5, qi = jq & 31;
                    int nj = (3 * bp + j) >> 6;
                    const float* v = xC[1 + j][ti];
#pragma unroll 8
                    for (int k = 0; k < 128; ++k) {
                        float4 w = Wx4[nj * 4096 + k * 32 + qi];
                        float xv = v[k];
                        acc.x += w.x * xv; acc.y += w.y * xv;
                        acc.z += w.z * xv; acc.w += w.w * xv;
                    }
                    int cq = j * 32 + qi;
                    ((__half2*)&axL[ti][0])[2 * cq] = __floats2half2_rn(acc.x, acc.y);
                    ((__half2*)&axL[ti][0])[2 * cq + 1] = __floats2half2_rn(acc.z, acc.w);
                }
            }
            __syncthreads();
        }

        if (tid < 384) {
            float4 acc = {0.f, 0.f, 0.f, 0.f};
            if (tid < 192) {
                int q = tid % 96, ks = tid / 96;
                dotq<WS>(wWr, q, 96, hS, ks * 64, 64, acc);
            } else {
                int t2 = tid - 192;
                int jq = t2 % 96, ks = t2 / 96;
                int j = jq >> 5, qi = jq & 31;
                int nj = (3 * bp + j) >> 6;
                dotq<WS>(wWh, nj * 4096 + qi, 32, sS + j * 128, ks * 64, 64, acc);
            }
            *(float4*)&part1[tid][0] = acc;
        }
        __syncthreads();

        if (tid < 192) {
            if (tid < 96) {
                int q = tid;
                float4 a0 = *(float4*)&part1[q][0];
                float4 a1 = *(float4*)&part1[q + 96][0];
                float2 g0 = h2f2(((const u32*)&gxL[tt][0])[2 * q]);
                float2 g1 = h2f2(((const u32*)&gxL[tt][0])[2 * q + 1]);
                float4 r;
                r.x = a0.x + a1.x + g0.x + biasL[4 * q];
                r.y = a0.y + a1.y + g0.y + biasL[4 * q + 1];
                r.z = a0.z + a1.z + g1.x + biasL[4 * q + 2];
                r.w = a0.w + a1.w + g1.y + biasL[4 * q + 3];
                *(float4*)&gS[4 * q] = r;
            } else {
                int cq = tid - 96;
                float4 a0 = *(float4*)&part1[192 + cq][0];
                float4 a1 = *(float4*)&part1[288 + cq][0];
                float2 g0 = h2f2(((const u32*)&axL[tt][0])[2 * cq]);
                float2 g1 = h2f2(((const u32*)&axL[tt][0])[2 * cq + 1]);
                float4 r;
                r.x = a0.x + a1.x + g0.x;
                r.y = a0.y + a1.y + g0.y;
                r.z = a0.z + a1.z + g1.x;
                r.w = a0.w + a1.w + g1.y;
                *(float4*)&aS[4 * cq] = r;
            }
        }
        __syncthreads();

        if (tid < 192) {
            int q = tid % 96, ks = tid / 96;
            int j = q >> 5, qi = q & 31;
            int nj = (3 * bp + j) >> 6;
            float4 acc = {0.f, 0.f, 0.f, 0.f};
            dotq<WS>(wDw, nj * 4096 + qi, 32, aS + j * 128, ks * 64, 64, acc);
            *(float4*)&part2[tid][0] = acc;
        } else if (tid >= 384) {
            int u = tid - 384;
            float gi = sigf(gS[u]);
            float gf = sigf(gS[128 + u]);
            float gc = sigf(gS[256 + u]);
            float cn = gf * cS[u] + gi * tanh_(gc);
            cS[u] = cn;
            tcS[u] = tanh_(cn);
        }
        __syncthreads();

        if (tid < 96) {
            int j = tid >> 5, o = (tid & 31) * 4;
            float4 a0 = *(float4*)&part2[tid][0];
            float4 a1 = *(float4*)&part2[tid + 96][0];
            float4 r;
            r.x = fmaxf(a0.x + a1.x + DbL[j][o], 0.f);
            r.y = fmaxf(a0.y + a1.y + DbL[j][o + 1], 0.f);
            r.z = fmaxf(a0.z + a1.z + DbL[j][o + 2], 0.f);
            r.w = fmaxf(a0.w + a1.w + DbL[j][o + 3], 0.f);
            *(float4*)&pS[4 * tid] = r;
        }
        __syncthreads();

        if (tid < 256) {
            int q = tid & 31, ks = tid >> 5;
            float4 acc = {0.f, 0.f, 0.f, 0.f};
            dotq<WS>(wAw, q, 32, pS, ks * 48, 48, acc);
            *(float4*)&part3[tid][0] = acc;
        } else if (tid < 384) {
            int e = tid - 256;
#pragma unroll
            for (int j = 0; j < 3; ++j) {
                int q = j * 128 + e;
                sS[q] = stkj[j][0][e] * pS[q] + stkj[j][1][e] * sS[q];
            }
        }
        __syncthreads();

        if (tid < 128) {
            int u = tid;
            float y = AbL[u];
#pragma unroll
            for (int ks = 0; ks < 8; ++ks) y += part3[ks * 32 + (u >> 2)][u & 3];
            float hn = sigf(y) * tcS[u];
            hS[u] = hn;
            outp[((size_t)bp * TT + t) * 128 + u] = hn;
        }
        __syncthreads();
    }
}

extern "C" void kernel_launch(void* const* d_in, const int* in_sizes, int n_in,
                              void* d_out, int out_size, void* d_ws, size_t ws_size,
                              hipStream_t stream) {
    const float* x    = (const float*)d_in[0];
    const float* Wk   = (const float*)d_in[1];
    const float* Wr   = (const float*)d_in[2];
    const float* bias = (const float*)d_in[3];
    const float* Wx   = (const float*)d_in[4];
    const float* Wh   = (const float*)d_in[5];
    const float* stk  = (const float*)d_in[6];
    const float* Dw   = (const float*)d_in[7];
    const float* Db   = (const float*)d_in[8];
    const float* Aw   = (const float*)d_in[9];
    const float* Ab   = (const float*)d_in[10];
    float* outp = (float*)d_out;

    const size_t needW  = 196608 * sizeof(__half);  // fp16 weights
    const size_t needW2 = needW + (size_t)BB * TT * 768 * sizeof(__half);  // +gax
    if (ws_size >= needW2) {
        __half* wt = (__half*)d_ws;
        __half* gax = wt + 196608;
        convert_w<<<dim3(384), dim3(512), 0, stream>>>(Wr, Wh, Dw, Aw, wt);
        gax_pre<<<dim3(BB, 64), dim3(384), 0, stream>>>(x, Wk, Wx, gax);
        tkan3<<<dim3(BB), dim3(512), 0, stream>>>(bias, stk, Db, Ab, wt, outp);
    } else if (ws_size >= needW) {
        __half* wt = (__half*)d_ws;
        convert_w<<<dim3(384), dim3(512), 0, stream>>>(Wr, Wh, Dw, Aw, wt);
        tkan<true><<<dim3(BB), dim3(512), 0, stream>>>(
            x, Wk, Wr, bias, Wx, Wh, stk, Dw, Db, Aw, Ab, wt, outp);
    } else {
        tkan<false><<<dim3(BB), dim3(512), 0, stream>>>(
            x, Wk, Wr, bias, Wx, Wh, stk, Dw, Db, Aw, Ab, (const __half*)nullptr,
            outp);
    }
}

// Round 3
// 13621.883 us; speedup vs baseline: 1.0363x; 1.0363x over previous
//
#include <hip/hip_runtime.h>
#include <hip/hip_fp16.h>

// TKANCell B=64,T=2048,D=128,U=128,NS=3 — fp32 in/out.
// 64 independent chains (tf.reshape routes sub-row r=3b'+j to batch b'=r/3).
// R8: R7's wreg[64] (128 VGPR) spilled to scratch (VGPR_Count=128 == array
// size; WRITE_SIZE +10.7MB scratch stores; VALUBusy halved) -> regression.
// Fix: smaller per-thread arrays (wrW[32]=64reg on 384thr K-split4,
// wrA[24]=48reg on 512thr K-split16), amdgpu_waves_per_eu(2,2) to pin the
// allocator at the 2-waves/SIMD reality (155KB LDS => 1 block/CU), and
// 3 barriers/step: S1 Wr(reg)+Wh(LDS) shfl-reduced; S2 Dw(LDS) || c-update;
// S3 Aw(reg) all-512 shfl-reduced, lanes<4 finalize h+outp, lanes>=4 s-update.

#define TT 2048
#define BB 64
#define TC 32

typedef unsigned int u32;

__device__ __forceinline__ float sigf(float x) { return 1.f / (1.f + __expf(-x)); }
__device__ __forceinline__ float tanh_(float x) { return 2.f / (1.f + __expf(-2.f * x)) - 1.f; }
__device__ __forceinline__ float2 h2f2(u32 u) {
    __half2 h = *(__half2*)&u;
    return __half22float2(h);
}

__device__ __forceinline__ void fma4(float4& acc, uint2 w, float xv) {
    float2 lo = h2f2(w.x), hi = h2f2(w.y);
    acc.x += lo.x * xv; acc.y += lo.y * xv;
    acc.z += hi.x * xv; acc.w += hi.y * xv;
}

// register-array dot: acc += Wcols[i] * v[i], i in [0,KN); v 16B-aligned LDS.
template <int KN>
__device__ __forceinline__ void dot_reg(const uint2* wr, const float* __restrict__ v,
                                        float4& acc) {
#pragma unroll
    for (int k = 0; k < KN; k += 4) {
        float4 vv = *(const float4*)&v[k];
        fma4(acc, wr[k + 0], vv.x);
        fma4(acc, wr[k + 1], vv.y);
        fma4(acc, wr[k + 2], vv.z);
        fma4(acc, wr[k + 3], vv.w);
    }
}

// LDS weight dot: acc += Wp[k*32] * v[k], k in [0,KN).
template <int KN>
__device__ __forceinline__ void dot_lds32(const uint2* Wp,
                                          const float* __restrict__ v, float4& acc) {
#pragma unroll
    for (int k = 0; k < KN; k += 4) {
        float4 vv = *(const float4*)&v[k];
        fma4(acc, Wp[(k + 0) * 32], vv.x);
        fma4(acc, Wp[(k + 1) * 32], vv.y);
        fma4(acc, Wp[(k + 2) * 32], vv.z);
        fma4(acc, Wp[(k + 3) * 32], vv.w);
    }
}

__device__ __forceinline__ void shred(float4& a, int m) {
    a.x += __shfl_xor(a.x, m, 64);
    a.y += __shfl_xor(a.y, m, 64);
    a.z += __shfl_xor(a.z, m, 64);
    a.w += __shfl_xor(a.w, m, 64);
}

// legacy dot for fallback kernel
template <bool WS>
__device__ __forceinline__ void dotq(const void* W, int idxBase, int stride,
                                     const float* __restrict__ v, int k0, int kn,
                                     float4& acc) {
    if (WS) {
        const uint2* Wp = (const uint2*)W;
#pragma unroll 8
        for (int k = k0; k < k0 + kn; ++k) {
            uint2 w = Wp[idxBase + k * stride];
            float2 lo = h2f2(w.x), hi = h2f2(w.y);
            float xv = v[k];
            acc.x += lo.x * xv; acc.y += lo.y * xv;
            acc.z += hi.x * xv; acc.w += hi.y * xv;
        }
    } else {
        const float4* Wp = (const float4*)W;
#pragma unroll 8
        for (int k = k0; k < k0 + kn; ++k) {
            float4 w = Wp[idxBase + k * stride];
            float xv = v[k];
            acc.x += w.x * xv; acc.y += w.y * xv;
            acc.z += w.z * xv; acc.w += w.w * xv;
        }
    }
}

// fp16 copy of Wr|Wh|Dw|Aw (each 49152 elems, layout preserved).
__global__ __launch_bounds__(512) void convert_w(
    const float* __restrict__ Wr, const float* __restrict__ Wh,
    const float* __restrict__ Dw, const float* __restrict__ Aw,
    __half* __restrict__ dst) {
    int g = blockIdx.x * 512 + threadIdx.x;  // 0..196607
    int seg = g / 49152, idx = g % 49152;
    const float* src = (seg == 0) ? Wr : (seg == 1) ? Wh : (seg == 2) ? Dw : Aw;
    dst[g] = __float2half(src[idx]);
}

// ===== pre-pass: gax[bp][t][768] fp16 = [x@Wk (384) | x@Wx slices (384)].
__global__ __launch_bounds__(384, 3) void gax_pre(
    const float* __restrict__ xg, const float* __restrict__ Wk,
    const float* __restrict__ Wx, __half* __restrict__ gax) {
    const int bp = blockIdx.x, tc = blockIdx.y, tid = threadIdx.x;
    const int t0 = tc * 32;
    __shared__ __align__(16) float xCt[4][128][32];  // 64KB, [v][k][ti]

    for (int f = tid; f < 4096; f += 384) {
        int v_ = f >> 10, ti = (f >> 5) & 31, kq = f & 31;
        int row = (v_ == 0) ? bp : ((3 * bp + (v_ - 1)) & 63);
        float4 w = ((const float4*)(xg + ((size_t)row * TT + t0 + ti) * 128))[kq];
        xCt[v_][4 * kq + 0][ti] = w.x;
        xCt[v_][4 * kq + 1][ti] = w.y;
        xCt[v_][4 * kq + 2][ti] = w.z;
        xCt[v_][4 * kq + 3][ti] = w.w;
    }
    __syncthreads();

    const float4* Wk4 = (const float4*)Wk;
    const float4* Wx4 = (const float4*)Wx;

    for (int task = tid; task < 768; task += 384) {
        int grp = task / 192, r = task % 192;
        int ti0 = grp * 8;
        const float4* Wp;
        int base, stride, v;
        if (r < 96) {
            Wp = Wk4; base = r; stride = 96; v = 0;
        } else {
            int jq = r - 96, j = jq >> 5, qi = jq & 31;
            int nj = (3 * bp + j) >> 6;
            Wp = Wx4; base = nj * 4096 + qi; stride = 32; v = 1 + j;
        }
        float4 acc[8];
#pragma unroll
        for (int i = 0; i < 8; ++i) acc[i] = make_float4(0.f, 0.f, 0.f, 0.f);
#pragma unroll 4
        for (int k = 0; k < 128; ++k) {
            float4 w = Wp[base + k * stride];
            float4 xa = *(const float4*)&xCt[v][k][ti0];
            float4 xb = *(const float4*)&xCt[v][k][ti0 + 4];
#pragma unroll
            for (int i = 0; i < 4; ++i) {
                float xv = (&xa.x)[i];
                acc[i].x += w.x * xv; acc[i].y += w.y * xv;
                acc[i].z += w.z * xv; acc[i].w += w.w * xv;
            }
#pragma unroll
            for (int i = 0; i < 4; ++i) {
                float xv = (&xb.x)[i];
                acc[4 + i].x += w.x * xv; acc[4 + i].y += w.y * xv;
                acc[4 + i].z += w.z * xv; acc[4 + i].w += w.w * xv;
            }
        }
#pragma unroll
        for (int i = 0; i < 8; ++i) {
            size_t off = ((size_t)bp * TT + (size_t)(t0 + ti0 + i)) * 768 + 4 * r;
            __half2 lo = __floats2half2_rn(acc[i].x, acc[i].y);
            __half2 hi = __floats2half2_rn(acc[i].z, acc[i].w);
            uint2 pk = make_uint2(*(u32*)&lo, *(u32*)&hi);
            *(uint2*)(gax + off) = pk;
        }
    }
}

// ===== R8 serial kernel =====
__global__ __launch_bounds__(512)
__attribute__((amdgpu_waves_per_eu(2, 2)))
void tkan4(
    const float* __restrict__ bias, const float* __restrict__ stk,
    const float* __restrict__ Db, const float* __restrict__ Ab,
    const __half* __restrict__ wt, float* __restrict__ outp) {
    const int bp = blockIdx.x, tid = threadIdx.x;
    const int w = tid >> 6, l = tid & 63;

    __shared__ uint2 WhL[8192];               // up to 2 slices (64KB)
    __shared__ uint2 DwL[8192];               // 64KB
    __shared__ __align__(16) uint2 gxS[1536]; // 8 steps x 192 uint2 (12KB)
    __shared__ __align__(16) float hS[128], cS[128], tcS[128];
    __shared__ __align__(16) float sS[384], aS[384], pS[384], gS[384];
    __shared__ __align__(16) float biasL[384], stkj[3][2][128];
    __shared__ __align__(16) float DbL[3][128], AbL[128];

    const int nj0 = (3 * bp) >> 6;
    const int nslice = ((3 * bp + 2) >> 6) - nj0 + 1;  // 1 or 2

    if (tid < 128) { hS[tid] = 0.f; cS[tid] = 0.f; AbL[tid] = Ab[tid]; }
    if (tid >= 128 && tid < 512) {
        int q = tid - 128;
        sS[q] = 0.f;
        biasL[q] = bias[q];
    }
    {
        int j = tid >> 7, o = tid & 127;
        if (j < 3) {
            int nj = (3 * bp + j) >> 6;
            stkj[j][0][o] = stk[nj * 256 + o];
            stkj[j][1][o] = stk[nj * 256 + 128 + o];
            DbL[j][o] = Db[nj * 128 + o];
        }
    }
    const uint2* wtWr = (const uint2*)wt;
    const uint2* wtWh = (const uint2*)(wt + 49152);
    const uint2* wtDw = (const uint2*)(wt + 98304);
    const uint2* wtAw = (const uint2*)(wt + 147456);
    for (int i = tid; i < nslice * 4096; i += 512) {
        int s = i >> 12, idx = i & 4095;
        WhL[i] = wtWh[(nj0 + s) * 4096 + idx];
        DwL[i] = wtDw[(nj0 + s) * 4096 + idx];
    }

    // ---- register-resident weights (uniform init on ALL threads; compile-
    // time-only indexing; allocator pinned by waves_per_eu(2,2)).
    // Wr: quad qW in [0,96), K chunk ks4 in [0,4) of 32. (waves 6,7 = dups)
    // Aw: quad qA in [0,32), K chunk ks16 in [0,16) of 24.
    const int lq = l & 15, ks4 = l >> 4;
    const int qW = (w % 6) * 16 + lq;
    const int qA = w * 4 + (l & 3), ks16 = l >> 2;
    uint2 wrW[32], wrA[24];
#pragma unroll
    for (int i = 0; i < 32; ++i) wrW[i] = wtWr[qW + (32 * ks4 + i) * 96];
#pragma unroll
    for (int i = 0; i < 24; ++i) wrA[i] = wtAw[qA + (24 * ks16 + i) * 32];

    const int jW = qW >> 5, qiW = qW & 31;
    const int sjW = ((3 * bp + jW) >> 6) - nj0;
    const uint2* WhB = WhL + sjW * 4096 + qiW + (32 * ks4) * 32;
    const uint2* DwB = DwL + sjW * 4096 + qiW + (32 * ks4) * 32;

    __syncthreads();

    const uint2* gaxRow = (const uint2*)(wt + 196608 + (size_t)bp * TT * 768);

    for (int t = 0; t < TT; ++t) {
        if ((t & 7) == 0) {
            const uint4* g4 = (const uint4*)(gaxRow + (size_t)t * 192);
            for (int i = tid; i < 768; i += 512) ((uint4*)gxS)[i] = g4[i];
            __syncthreads();
        }

        // ===== S1 (waves 0-5): gates (Wr, reg) + agg-in (Wh, LDS), K-split 4,
        // reduced via shfl_xor(16)+(32); lanes l<16 add gax(+bias), write gS/aS.
        if (w < 6) {
            float4 accW = {0.f, 0.f, 0.f, 0.f};
            float4 accH = {0.f, 0.f, 0.f, 0.f};
            dot_reg<32>(wrW, hS + 32 * ks4, accW);
            dot_lds32<32>(WhB, sS + jW * 128 + 32 * ks4, accH);
            shred(accW, 16); shred(accH, 16);
            shred(accW, 32); shred(accH, 32);
            if (l < 16) {
                uint2 gv = gxS[(t & 7) * 192 + qW];
                uint2 av = gxS[(t & 7) * 192 + 96 + qW];
                float2 g0 = h2f2(gv.x), g1 = h2f2(gv.y);
                float2 a0 = h2f2(av.x), a1 = h2f2(av.y);
                float4 rg, ra;
                rg.x = accW.x + g0.x + biasL[4 * qW];
                rg.y = accW.y + g0.y + biasL[4 * qW + 1];
                rg.z = accW.z + g1.x + biasL[4 * qW + 2];
                rg.w = accW.w + g1.y + biasL[4 * qW + 3];
                ra.x = accH.x + a0.x;
                ra.y = accH.y + a0.y;
                ra.z = accH.z + a1.x;
                ra.w = accH.w + a1.y;
                *(float4*)&gS[4 * qW] = rg;
                *(float4*)&aS[4 * qW] = ra;
            }
        }
        __syncthreads();

        // ===== S2 (waves 0-5): sub-dense (Dw, LDS) shfl-reduced -> pS;
        // (waves 6-7): c-update.
        if (w < 6) {
            float4 acc = {0.f, 0.f, 0.f, 0.f};
            dot_lds32<32>(DwB, aS + jW * 128 + 32 * ks4, acc);
            shred(acc, 16);
            shred(acc, 32);
            if (l < 16) {
                int o = 4 * qiW;
                float4 r;
                r.x = fmaxf(acc.x + DbL[jW][o], 0.f);
                r.y = fmaxf(acc.y + DbL[jW][o + 1], 0.f);
                r.z = fmaxf(acc.z + DbL[jW][o + 2], 0.f);
                r.w = fmaxf(acc.w + DbL[jW][o + 3], 0.f);
                *(float4*)&pS[4 * qW] = r;
            }
        } else {
            int u = tid - 384;  // 0..127
            float gi = sigf(gS[u]);
            float gf = sigf(gS[128 + u]);
            float gc = sigf(gS[256 + u]);
            float cn = gf * cS[u] + gi * tanh_(gc);
            cS[u] = cn;
            tcS[u] = tanh_(cn);
        }
        __syncthreads();

        // ===== S3 (all 512): aggregate (Aw, reg, K-split 16) shfl-reduced;
        // lanes l<4 finalize h + write outp; lanes l>=4 do s-update.
        {
            float4 acc = {0.f, 0.f, 0.f, 0.f};
            dot_reg<24>(wrA, pS + 24 * ks16, acc);
            shred(acc, 4);
            shred(acc, 8);
            shred(acc, 16);
            shred(acc, 32);
            if (l < 4) {
                float4 ab = *(const float4*)&AbL[4 * qA];
                float4 tc = *(const float4*)&tcS[4 * qA];
                float4 hn;
                hn.x = sigf(acc.x + ab.x) * tc.x;
                hn.y = sigf(acc.y + ab.y) * tc.y;
                hn.z = sigf(acc.z + ab.z) * tc.z;
                hn.w = sigf(acc.w + ab.w) * tc.w;
                *(float4*)&hS[4 * qA] = hn;
                *(float4*)&outp[((size_t)bp * TT + t) * 128 + 4 * qA] = hn;
            } else if (l < 52) {
                int q = w * 48 + (l - 4);  // 0..383
                int jj = q >> 7, e = q & 127;
                sS[q] = stkj[jj][0][e] * pS[q] + stkj[jj][1][e] * sS[q];
            }
        }
        __syncthreads();
    }
}

// ===== Verified fallback (unchanged): chunk-phase kernel =====
template <bool WS>
__global__ __launch_bounds__(512, 1) void tkan(
    const float* __restrict__ xg, const float* __restrict__ Wk,
    const float* __restrict__ Wr, const float* __restrict__ bias,
    const float* __restrict__ Wx, const float* __restrict__ Wh,
    const float* __restrict__ stk, const float* __restrict__ Dw,
    const float* __restrict__ Db, const float* __restrict__ Aw,
    const float* __restrict__ Ab, const __half* __restrict__ wt,
    float* __restrict__ outp) {
    const int bp = blockIdx.x, tid = threadIdx.x;

    __shared__ float xC[4][TC][128];
    __shared__ __half gxL[TC][384];
    __shared__ __half axL[TC][384];
    __shared__ float hS[128], cS[128], tcS[128];
    __shared__ float sS[384], aS[384], pS[384], gS[384];
    __shared__ float part1[384][4], part2[192][4], part3[256][4];
    __shared__ float biasL[384], stkj[3][2][128], DbL[3][128], AbL[128];
    __shared__ float dummy[WS ? 4 : 4096];

    if (tid < 128) { hS[tid] = 0.f; cS[tid] = 0.f; AbL[tid] = Ab[tid]; }
    if (tid >= 128 && tid < 512) {
        int q = tid - 128;
        sS[q] = 0.f;
        biasL[q] = bias[q];
    }
    {
        int j = tid >> 7, o = tid & 127;
        if (j < 3) {
            int nj = (3 * bp + j) >> 6;
            stkj[j][0][o] = stk[nj * 256 + o];
            stkj[j][1][o] = stk[nj * 256 + 128 + o];
            DbL[j][o] = Db[nj * 128 + o];
        }
    }
    if (bias[0] > 1e30f) { dummy[tid & 3] = 1.f; }
    __syncthreads();

    const float4* Wk4 = (const float4*)Wk;
    const float4* Wx4 = (const float4*)Wx;
    const void* wWr = WS ? (const void*)(wt)          : (const void*)Wr;
    const void* wWh = WS ? (const void*)(wt + 49152)  : (const void*)Wh;
    const void* wDw = WS ? (const void*)(wt + 98304)  : (const void*)Dw;
    const void* wAw = WS ? (const void*)(wt + 147456) : (const void*)Aw;

    for (int t = 0; t < TT; ++t) {
        int tt = t & (TC - 1);
        if (tt == 0) {
            for (int f = tid; f < 4096; f += 512) {
                int v_ = f >> 10, ti = (f >> 5) & 31, kq = f & 31;
                int row = (v_ == 0) ? bp : ((3 * bp + (v_ - 1)) & 63);
                float4 w = ((const float4*)(xg + ((size_t)row * TT + t + ti) * 128))[kq];
                float* d = &xC[v_][ti][kq * 4];
                d[0] = w.x; d[1] = w.y; d[2] = w.z; d[3] = w.w;
            }
            __syncthreads();
            for (int ct = tid; ct < TC * 192; ct += 512) {
                int ti = ct / 192, r = ct % 192;
                float4 acc = {0.f, 0.f, 0.f, 0.f};
                if (r < 96) {
                    const float* v = xC[0][ti];
#pragma unroll 8
                    for (int k = 0; k < 128; ++k) {
                        float4 w = Wk4[k * 96 + r];
                        float xv = v[k];
                        acc.x += w.x * xv; acc.y += w.y * xv;
                        acc.z += w.z * xv; acc.w += w.w * xv;
                    }
                    int qout = r;
                    ((__half2*)&gxL[ti][0])[2 * qout] = __floats2half2_rn(acc.x, acc.y);
                    ((__half2*)&gxL[ti][0])[2 * qout + 1] = __floats2half2_rn(acc.z, acc.w);
                } else {
                    int jq = r - 96, j = jq >> 5, qi = jq & 31;
                    int nj = (3 * bp + j) >> 6;
                    const float* v = xC[1 + j][ti];
#pragma unroll 8
                    for (int k = 0; k < 128; ++k) {
                        float4 w = Wx4[nj * 4096 + k * 32 + qi];
                        float xv = v[k];
                        acc.x += w.x * xv; acc.y += w.y * xv;
                        acc.z += w.z * xv; acc.w += w.w * xv;
                    }
                    int cq = j * 32 + qi;
                    ((__half2*)&axL[ti][0])[2 * cq] = __floats2half2_rn(acc.x, acc.y);
                    ((__half2*)&axL[ti][0])[2 * cq + 1] = __floats2half2_rn(acc.z, acc.w);
                }
            }
            __syncthreads();
        }

        if (tid < 384) {
            float4 acc = {0.f, 0.f, 0.f, 0.f};
            if (tid < 192) {
                int q = tid % 96, ks = tid / 96;
                dotq<WS>(wWr, q, 96, hS, ks * 64, 64, acc);
            } else {
                int t2 = tid - 192;
                int jq = t2 % 96, ks = t2 / 96;
                int j = jq >> 5, qi = jq & 31;
                int nj = (3 * bp + j) >> 6;
                dotq<WS>(wWh, nj * 4096 + qi, 32, sS + j * 128, ks * 64, 64, acc);
            }
            *(float4*)&part1[tid][0] = acc;
        }
        __syncthreads();

        if (tid < 192) {
            if (tid < 96) {
                int q = tid;
                float4 a0 = *(float4*)&part1[q][0];
                float4 a1 = *(float4*)&part1[q + 96][0];
                float2 g0 = h2f2(((const u32*)&gxL[tt][0])[2 * q]);
                float2 g1 = h2f2(((const u32*)&gxL[tt][0])[2 * q + 1]);
                float4 r;
                r.x = a0.x + a1.x + g0.x + biasL[4 * q];
                r.y = a0.y + a1.y + g0.y + biasL[4 * q + 1];
                r.z = a0.z + a1.z + g1.x + biasL[4 * q + 2];
                r.w = a0.w + a1.w + g1.y + biasL[4 * q + 3];
                *(float4*)&gS[4 * q] = r;
            } else {
                int cq = tid - 96;
                float4 a0 = *(float4*)&part1[192 + cq][0];
                float4 a1 = *(float4*)&part1[288 + cq][0];
                float2 g0 = h2f2(((const u32*)&axL[tt][0])[2 * cq]);
                float2 g1 = h2f2(((const u32*)&axL[tt][0])[2 * cq + 1]);
                float4 r;
                r.x = a0.x + a1.x + g0.x;
                r.y = a0.y + a1.y + g0.y;
                r.z = a0.z + a1.z + g1.x;
                r.w = a0.w + a1.w + g1.y;
                *(float4*)&aS[4 * cq] = r;
            }
        }
        __syncthreads();

        if (tid < 192) {
            int q = tid % 96, ks = tid / 96;
            int j = q >> 5, qi = q & 31;
            int nj = (3 * bp + j) >> 6;
            float4 acc = {0.f, 0.f, 0.f, 0.f};
            dotq<WS>(wDw, nj * 4096 + qi, 32, aS + j * 128, ks * 64, 64, acc);
            *(float4*)&part2[tid][0] = acc;
        } else if (tid >= 384) {
            int u = tid - 384;
            float gi = sigf(gS[u]);
            float gf = sigf(gS[128 + u]);
            float gc = sigf(gS[256 + u]);
            float cn = gf * cS[u] + gi * tanh_(gc);
            cS[u] = cn;
            tcS[u] = tanh_(cn);
        }
        __syncthreads();

        if (tid < 96) {
            int j = tid >> 5, o = (tid & 31) * 4;
            float4 a0 = *(float4*)&part2[tid][0];
            float4 a1 = *(float4*)&part2[tid + 96][0];
            float4 r;
            r.x = fmaxf(a0.x + a1.x + DbL[j][o], 0.f);
            r.y = fmaxf(a0.y + a1.y + DbL[j][o + 1], 0.f);
            r.z = fmaxf(a0.z + a1.z + DbL[j][o + 2], 0.f);
            r.w = fmaxf(a0.w + a1.w + DbL[j][o + 3], 0.f);
            *(float4*)&pS[4 * tid] = r;
        }
        __syncthreads();

        if (tid < 256) {
            int q = tid & 31, ks = tid >> 5;
            float4 acc = {0.f, 0.f, 0.f, 0.f};
            dotq<WS>(wAw, q, 32, pS, ks * 48, 48, acc);
            *(float4*)&part3[tid][0] = acc;
        } else if (tid < 384) {
            int e = tid - 256;
#pragma unroll
            for (int j = 0; j < 3; ++j) {
                int q = j * 128 + e;
                sS[q] = stkj[j][0][e] * pS[q] + stkj[j][1][e] * sS[q];
            }
        }
        __syncthreads();

        if (tid < 128) {
            int u = tid;
            float y = AbL[u];
#pragma unroll
            for (int ks = 0; ks < 8; ++ks) y += part3[ks * 32 + (u >> 2)][u & 3];
            float hn = sigf(y) * tcS[u];
            hS[u] = hn;
            outp[((size_t)bp * TT + t) * 128 + u] = hn;
        }
        __syncthreads();
    }
}

extern "C" void kernel_launch(void* const* d_in, const int* in_sizes, int n_in,
                              void* d_out, int out_size, void* d_ws, size_t ws_size,
                              hipStream_t stream) {
    const float* x    = (const float*)d_in[0];
    const float* Wk   = (const float*)d_in[1];
    const float* Wr   = (const float*)d_in[2];
    const float* bias = (const float*)d_in[3];
    const float* Wx   = (const float*)d_in[4];
    const float* Wh   = (const float*)d_in[5];
    const float* stk  = (const float*)d_in[6];
    const float* Dw   = (const float*)d_in[7];
    const float* Db   = (const float*)d_in[8];
    const float* Aw   = (const float*)d_in[9];
    const float* Ab   = (const float*)d_in[10];
    float* outp = (float*)d_out;

    const size_t needW  = 196608 * sizeof(__half);  // fp16 weights
    const size_t needW2 = needW + (size_t)BB * TT * 768 * sizeof(__half);  // +gax
    if (ws_size >= needW2) {
        __half* wt = (__half*)d_ws;
        __half* gax = wt + 196608;
        convert_w<<<dim3(384), dim3(512), 0, stream>>>(Wr, Wh, Dw, Aw, wt);
        gax_pre<<<dim3(BB, 64), dim3(384), 0, stream>>>(x, Wk, Wx, gax);
        tkan4<<<dim3(BB), dim3(512), 0, stream>>>(bias, stk, Db, Ab, wt, outp);
    } else if (ws_size >= needW) {
        __half* wt = (__half*)d_ws;
        convert_w<<<dim3(384), dim3(512), 0, stream>>>(Wr, Wh, Dw, Aw, wt);
        tkan<true><<<dim3(BB), dim3(512), 0, stream>>>(
            x, Wk, Wr, bias, Wx, Wh, stk, Dw, Db, Aw, Ab, wt, outp);
    } else {
        tkan<false><<<dim3(BB), dim3(512), 0, stream>>>(
            x, Wk, Wr, bias, Wx, Wh, stk, Dw, Db, Aw, Ab, (const __half*)nullptr,
            outp);
    }
}

// Round 4
// 8997.661 us; speedup vs baseline: 1.5689x; 1.5139x over previous
//
#include <hip/hip_runtime.h>
#include <hip/hip_fp16.h>

// TKANCell B=64,T=2048,D=128,U=128,NS=3 — fp32 in/out.
// 64 independent chains (tf.reshape routes sub-row r=3b'+j to batch b'=r/3).
// R9: R7/R8 proved >=112 regs/thread of weights always spills (VGPR pinned
// at 128, scratch WRITE +7-11MB, VALUBusy ~6-7%). New structure exploits that
// the s-recurrence is independent of h/c:
//   gax_pre2 (parallel): gx=x@Wk, ax=x@Wx -> 2 fp16 buffers (201.33MB total,
//     fits the workspace already proven >=201.72MB in R1-R3).
//   subrec  (serial): s-recurrence; Wh+Dw slices LDS-resident (131KB worst
//     case, converted in-kernel); writes p fp16 IN PLACE over consumed ax.
//   aggmm   (parallel): o_pre = p@Aw + Ab; Aw in LDS; o_pre fp32 in place
//     over p (each block stages its p rows before overwriting).
//   gaterec (serial): gate recurrence; Wr LDS-resident (96KB); h=sig(o_pre)*
//     tanh(c); writes outp.
// Serial loops: all weight reads from LDS, gx/ax/o_pre streams staged in
// 8-step chunks, 2 barriers/step, no per-thread weight arrays -> no spills.

#define TT 2048
#define BB 64
#define TC 32

typedef unsigned int u32;

__device__ __forceinline__ float sigf(float x) { return 1.f / (1.f + __expf(-x)); }
__device__ __forceinline__ float tanh_(float x) { return 2.f / (1.f + __expf(-2.f * x)) - 1.f; }
__device__ __forceinline__ float2 h2f2(u32 u) {
    __half2 h = *(__half2*)&u;
    return __half22float2(h);
}

__device__ __forceinline__ void fma4(float4& acc, uint2 w, float xv) {
    float2 lo = h2f2(w.x), hi = h2f2(w.y);
    acc.x += lo.x * xv; acc.y += lo.y * xv;
    acc.z += hi.x * xv; acc.w += hi.y * xv;
}

// LDS fp16 weight dot: acc += Wp[k*stride] * v[k], k in [0,KN).
template <int KN>
__device__ __forceinline__ void dot_lds(const uint2* Wp, int stride,
                                        const float* __restrict__ v, float4& acc) {
#pragma unroll
    for (int k = 0; k < KN; k += 4) {
        float4 vv = *(const float4*)&v[k];
        fma4(acc, Wp[(k + 0) * stride], vv.x);
        fma4(acc, Wp[(k + 1) * stride], vv.y);
        fma4(acc, Wp[(k + 2) * stride], vv.z);
        fma4(acc, Wp[(k + 3) * stride], vv.w);
    }
}

__device__ __forceinline__ void shred(float4& a, int m) {
    a.x += __shfl_xor(a.x, m, 64);
    a.y += __shfl_xor(a.y, m, 64);
    a.z += __shfl_xor(a.z, m, 64);
    a.w += __shfl_xor(a.w, m, 64);
}

// legacy dot for fallback kernel
template <bool WS>
__device__ __forceinline__ void dotq(const void* W, int idxBase, int stride,
                                     const float* __restrict__ v, int k0, int kn,
                                     float4& acc) {
    if (WS) {
        const uint2* Wp = (const uint2*)W;
#pragma unroll 8
        for (int k = k0; k < k0 + kn; ++k) {
            uint2 w = Wp[idxBase + k * stride];
            float2 lo = h2f2(w.x), hi = h2f2(w.y);
            float xv = v[k];
            acc.x += lo.x * xv; acc.y += lo.y * xv;
            acc.z += hi.x * xv; acc.w += hi.y * xv;
        }
    } else {
        const float4* Wp = (const float4*)W;
#pragma unroll 8
        for (int k = k0; k < k0 + kn; ++k) {
            float4 w = Wp[idxBase + k * stride];
            float xv = v[k];
            acc.x += w.x * xv; acc.y += w.y * xv;
            acc.z += w.z * xv; acc.w += w.w * xv;
        }
    }
}

// fp16 copy of Wr|Wh|Dw|Aw (fallback tier only).
__global__ __launch_bounds__(512) void convert_w(
    const float* __restrict__ Wr, const float* __restrict__ Wh,
    const float* __restrict__ Dw, const float* __restrict__ Aw,
    __half* __restrict__ dst) {
    int g = blockIdx.x * 512 + threadIdx.x;  // 0..196607
    int seg = g / 49152, idx = g % 49152;
    const float* src = (seg == 0) ? Wr : (seg == 1) ? Wh : (seg == 2) ? Dw : Aw;
    dst[g] = __float2half(src[idx]);
}

// ===== pre-pass: gx[bp][t][96quads] = x@Wk ; ax[bp][t][96quads] = x@Wx.
__global__ __launch_bounds__(384, 3) void gax_pre2(
    const float* __restrict__ xg, const float* __restrict__ Wk,
    const float* __restrict__ Wx, uint2* __restrict__ gxb,
    uint2* __restrict__ axb) {
    const int bp = blockIdx.x, tc = blockIdx.y, tid = threadIdx.x;
    const int t0 = tc * 32;
    __shared__ __align__(16) float xCt[4][128][32];  // 64KB, [v][k][ti]

    for (int f = tid; f < 4096; f += 384) {
        int v_ = f >> 10, ti = (f >> 5) & 31, kq = f & 31;
        int row = (v_ == 0) ? bp : ((3 * bp + (v_ - 1)) & 63);
        float4 w = ((const float4*)(xg + ((size_t)row * TT + t0 + ti) * 128))[kq];
        xCt[v_][4 * kq + 0][ti] = w.x;
        xCt[v_][4 * kq + 1][ti] = w.y;
        xCt[v_][4 * kq + 2][ti] = w.z;
        xCt[v_][4 * kq + 3][ti] = w.w;
    }
    __syncthreads();

    const float4* Wk4 = (const float4*)Wk;
    const float4* Wx4 = (const float4*)Wx;

    for (int task = tid; task < 768; task += 384) {
        int grp = task / 192, r = task % 192;
        int ti0 = grp * 8;
        const float4* Wp;
        int base, stride, v;
        if (r < 96) {
            Wp = Wk4; base = r; stride = 96; v = 0;
        } else {
            int jq = r - 96, j = jq >> 5, qi = jq & 31;
            int nj = (3 * bp + j) >> 6;
            Wp = Wx4; base = nj * 4096 + qi; stride = 32; v = 1 + j;
        }
        float4 acc[8];
#pragma unroll
        for (int i = 0; i < 8; ++i) acc[i] = make_float4(0.f, 0.f, 0.f, 0.f);
#pragma unroll 4
        for (int k = 0; k < 128; ++k) {
            float4 w = Wp[base + k * stride];
            float4 xa = *(const float4*)&xCt[v][k][ti0];
            float4 xb = *(const float4*)&xCt[v][k][ti0 + 4];
#pragma unroll
            for (int i = 0; i < 4; ++i) {
                float xv = (&xa.x)[i];
                acc[i].x += w.x * xv; acc[i].y += w.y * xv;
                acc[i].z += w.z * xv; acc[i].w += w.w * xv;
            }
#pragma unroll
            for (int i = 0; i < 4; ++i) {
                float xv = (&xb.x)[i];
                acc[4 + i].x += w.x * xv; acc[4 + i].y += w.y * xv;
                acc[4 + i].z += w.z * xv; acc[4 + i].w += w.w * xv;
            }
        }
#pragma unroll
        for (int i = 0; i < 8; ++i) {
            size_t rowo = ((size_t)bp * TT + (size_t)(t0 + ti0 + i)) * 96;
            __half2 lo = __floats2half2_rn(acc[i].x, acc[i].y);
            __half2 hi = __floats2half2_rn(acc[i].z, acc[i].w);
            uint2 pk = make_uint2(*(u32*)&lo, *(u32*)&hi);
            if (r < 96) gxb[rowo + r] = pk;
            else        axb[rowo + (r - 96)] = pk;
        }
    }
}

// ===== subrec: s-recurrence. Wh/Dw slices LDS-resident; p fp16 written in
// place over consumed ax. 2 barriers/step.
__global__ __launch_bounds__(512) void subrec(
    const float* __restrict__ Wh, const float* __restrict__ Dw,
    const float* __restrict__ stk, const float* __restrict__ Db,
    uint2* __restrict__ axp) {
    const int bp = blockIdx.x, tid = threadIdx.x;
    const int w = tid >> 6, l = tid & 63;
    const int ks4 = l >> 4;                 // K chunk of 32
    const int qW = (w % 6) * 16 + (l & 15); // output quad 0..95
    const int j = qW >> 5, qi = qW & 31;

    __shared__ uint2 WhL[8192];             // up to 2 slices (64KB)
    __shared__ uint2 DwL[8192];             // 64KB
    __shared__ __align__(16) uint2 axC[768];   // 8 steps x 96 (6KB)
    __shared__ __align__(16) uint2 pOut[768];  // 6KB
    __shared__ __align__(16) float sS[384], aS[384];
    __shared__ float stkh[3][128], stkx[3][128], DbL[3][128];

    const int nj0 = (3 * bp) >> 6;
    const int nslice = ((3 * bp + 2) >> 6) - nj0 + 1;  // 1 or 2

    if (tid < 384) sS[tid] = 0.f;
    {
        int jj = tid >> 7, o = tid & 127;
        if (jj < 3) {
            int nj = (3 * bp + jj) >> 6;
            stkh[jj][o] = stk[nj * 256 + o];
            stkx[jj][o] = stk[nj * 256 + 128 + o];
            DbL[jj][o] = Db[nj * 128 + o];
        }
    }
    // stage Wh/Dw fp32 -> fp16 LDS (layout [slice][k*32+qi], as verified)
    for (int i = tid; i < nslice * 4096; i += 512) {
        int s = i >> 12, idx = i & 4095;
        float4 a = ((const float4*)Wh)[(nj0 + s) * 4096 + idx];
        float4 b = ((const float4*)Dw)[(nj0 + s) * 4096 + idx];
        __half2 alo = __floats2half2_rn(a.x, a.y), ahi = __floats2half2_rn(a.z, a.w);
        __half2 blo = __floats2half2_rn(b.x, b.y), bhi = __floats2half2_rn(b.z, b.w);
        WhL[i] = make_uint2(*(u32*)&alo, *(u32*)&ahi);
        DwL[i] = make_uint2(*(u32*)&blo, *(u32*)&bhi);
    }

    const int sj = ((3 * bp + j) >> 6) - nj0;
    const uint2* WhB = WhL + sj * 4096 + qi + (32 * ks4) * 32;
    const uint2* DwB = DwL + sj * 4096 + qi + (32 * ks4) * 32;
    uint2* rowBase = axp + (size_t)bp * TT * 96;

    for (int t = 0; t < TT; ++t) {
        int tt = t & 7;
        if (tt == 0) {
            __syncthreads();  // prior phase2 pOut writes + axC consumers done
            if (t) {          // flush p chunk [t-8, t)
                uint2* dst = rowBase + (size_t)(t - 8) * 96;
                for (int i = tid; i < 768; i += 512) dst[i] = pOut[i];
            }
            const uint2* src = rowBase + (size_t)t * 96;
            for (int i = tid; i < 768; i += 512) axC[i] = src[i];
            __syncthreads();
        }

        // phase1: agg = s@Wh + ax
        if (w < 6) {
            float4 acc = {0.f, 0.f, 0.f, 0.f};
            dot_lds<32>(WhB, 32, sS + j * 128 + 32 * ks4, acc);
            shred(acc, 16);
            shred(acc, 32);
            if (l < 16) {
                uint2 av = axC[tt * 96 + qW];
                float2 a0 = h2f2(av.x), a1 = h2f2(av.y);
                float4 r;
                r.x = acc.x + a0.x;
                r.y = acc.y + a0.y;
                r.z = acc.z + a1.x;
                r.w = acc.w + a1.y;
                *(float4*)&aS[4 * qW] = r;
            }
        }
        __syncthreads();

        // phase2: p = relu(agg@Dw + Db); s = rh*p + rx*s; pack p fp16
        if (w < 6) {
            float4 acc = {0.f, 0.f, 0.f, 0.f};
            dot_lds<32>(DwB, 32, aS + j * 128 + 32 * ks4, acc);
            shred(acc, 16);
            shred(acc, 32);
            if (l < 16) {
                int o = 4 * qi;
                float4 p4;
                p4.x = fmaxf(acc.x + DbL[j][o], 0.f);
                p4.y = fmaxf(acc.y + DbL[j][o + 1], 0.f);
                p4.z = fmaxf(acc.z + DbL[j][o + 2], 0.f);
                p4.w = fmaxf(acc.w + DbL[j][o + 3], 0.f);
                float4 so = *(float4*)&sS[4 * qW];
                float4 sn;
                sn.x = stkh[j][o] * p4.x + stkx[j][o] * so.x;
                sn.y = stkh[j][o + 1] * p4.y + stkx[j][o + 1] * so.y;
                sn.z = stkh[j][o + 2] * p4.z + stkx[j][o + 2] * so.z;
                sn.w = stkh[j][o + 3] * p4.w + stkx[j][o + 3] * so.w;
                *(float4*)&sS[4 * qW] = sn;
                __half2 lo = __floats2half2_rn(p4.x, p4.y);
                __half2 hi = __floats2half2_rn(p4.z, p4.w);
                pOut[tt * 96 + qW] = make_uint2(*(u32*)&lo, *(u32*)&hi);
            }
        }
        __syncthreads();
    }
    // final flush [2040, 2048)
    {
        uint2* dst = rowBase + (size_t)(TT - 8) * 96;
        for (int i = tid; i < 768; i += 512) dst[i] = pOut[i];
    }
}

// ===== aggmm: o_pre = p@Aw + Ab (fp32), written in place over p rows.
// grid (64 chains, 16 tgroups of 128); 256 thr; Aw in LDS; p staged 32t fp32.
__global__ __launch_bounds__(256) void aggmm(
    const float* __restrict__ Aw, const float* __restrict__ Ab,
    uint2* __restrict__ axp) {
    const int bp = blockIdx.x, tg = blockIdx.y, tid = threadIdx.x;
    __shared__ uint2 AwL[12288];                 // [k*32+q] 96KB
    __shared__ __align__(16) float pT[32][384];  // 48KB
    __shared__ float AbL[128];

    for (int i = tid; i < 12288; i += 256) {
        float4 a = ((const float4*)Aw)[i];  // Aw[k][4q..]: i = k*32+q
        __half2 lo = __floats2half2_rn(a.x, a.y), hi = __floats2half2_rn(a.z, a.w);
        AwL[i] = make_uint2(*(u32*)&lo, *(u32*)&hi);
    }
    if (tid < 128) AbL[tid] = Ab[tid];

    uint2* rowBase = axp + (size_t)bp * TT * 96;
    for (int sc = 0; sc < 4; ++sc) {
        int t0 = tg * 128 + sc * 32;
        __syncthreads();  // pT free from previous subchunk's readers
        for (int i = tid; i < 3072; i += 256) {
            int trow = i / 96, q = i % 96;
            uint2 v = rowBase[(size_t)(t0 + trow) * 96 + q];
            float2 lo = h2f2(v.x), hi = h2f2(v.y);
            pT[trow][4 * q] = lo.x;
            pT[trow][4 * q + 1] = lo.y;
            pT[trow][4 * q + 2] = hi.x;
            pT[trow][4 * q + 3] = hi.y;
        }
        __syncthreads();
#pragma unroll
        for (int it = 0; it < 4; ++it) {
            int task = tid + 256 * it;
            int trow = task >> 5, q = task & 31;
            const float* pv = &pT[trow][0];
            float4 acc = {0.f, 0.f, 0.f, 0.f};
#pragma unroll 4
            for (int k = 0; k < 384; k += 4) {
                float4 vv = *(const float4*)&pv[k];
                fma4(acc, AwL[(k + 0) * 32 + q], vv.x);
                fma4(acc, AwL[(k + 1) * 32 + q], vv.y);
                fma4(acc, AwL[(k + 2) * 32 + q], vv.z);
                fma4(acc, AwL[(k + 3) * 32 + q], vv.w);
            }
            float* dst = (float*)(rowBase + (size_t)(t0 + trow) * 96);
            float4 r;
            r.x = acc.x + AbL[4 * q];
            r.y = acc.y + AbL[4 * q + 1];
            r.z = acc.z + AbL[4 * q + 2];
            r.w = acc.w + AbL[4 * q + 3];
            *(float4*)(dst + 4 * q) = r;
        }
    }
}

// ===== gaterec: gate recurrence. Wr LDS-resident; h = sig(o_pre)*tanh(c).
__global__ __launch_bounds__(512) void gaterec(
    const float* __restrict__ Wr, const float* __restrict__ bias,
    const uint2* __restrict__ gxb, const uint2* __restrict__ axp,
    float* __restrict__ outp) {
    const int bp = blockIdx.x, tid = threadIdx.x;
    const int w = tid >> 6, l = tid & 63;
    const int ks4 = l >> 4;
    const int qW = (w % 6) * 16 + (l & 15);

    __shared__ uint2 WrL[12288];                // [k*96+q] 96KB
    __shared__ __align__(16) uint2 gxC[768];    // 8 x 96 (6KB)
    __shared__ __align__(16) float opC[1024];   // 8 x 128 (4KB)
    __shared__ __align__(16) float hS[128], cS[128], gS[384];
    __shared__ float biasL[384];

    if (tid < 128) { hS[tid] = 0.f; cS[tid] = 0.f; }
    if (tid < 384) biasL[tid] = bias[tid];
    for (int i = tid; i < 12288; i += 512) {
        int k = i / 96, q = i % 96;
        float4 a = ((const float4*)Wr)[k * 96 + q];
        __half2 lo = __floats2half2_rn(a.x, a.y), hi = __floats2half2_rn(a.z, a.w);
        WrL[i] = make_uint2(*(u32*)&lo, *(u32*)&hi);
    }

    const uint2* WrB = WrL + qW + (32 * ks4) * 96;
    const uint2* gxRow = gxb + (size_t)bp * TT * 96;
    const uint2* opRow = axp + (size_t)bp * TT * 96;

    for (int t = 0; t < TT; ++t) {
        int tt = t & 7;
        if (tt == 0) {
            __syncthreads();
            for (int i = tid; i < 768; i += 512)
                gxC[i] = gxRow[(size_t)t * 96 + i];
            for (int i = tid; i < 256; i += 512) {
                int row = i >> 5, f4 = i & 31;
                const float4* src = (const float4*)(opRow + (size_t)(t + row) * 96);
                *(float4*)&opC[row * 128 + 4 * f4] = src[f4];
            }
            // threads 256..511 handle rows 2..7 of opC
            for (int i = tid + 256; i < 256 + 192; i += 512) {}
            for (int i = tid; i < 256; i += 512) {}
            // (single loop below covers all 256 float4 tasks)
            __syncthreads();
        }

        // phase1: gates_pre = h@Wr + gx + bias
        if (w < 6) {
            float4 acc = {0.f, 0.f, 0.f, 0.f};
            dot_lds<32>(WrB, 96, hS + 32 * ks4, acc);
            shred(acc, 16);
            shred(acc, 32);
            if (l < 16) {
                uint2 gv = gxC[tt * 96 + qW];
                float2 g0 = h2f2(gv.x), g1 = h2f2(gv.y);
                float4 r;
                r.x = acc.x + g0.x + biasL[4 * qW];
                r.y = acc.y + g0.y + biasL[4 * qW + 1];
                r.z = acc.z + g1.x + biasL[4 * qW + 2];
                r.w = acc.w + g1.y + biasL[4 * qW + 3];
                *(float4*)&gS[4 * qW] = r;
            }
        }
        __syncthreads();

        // phase2: c,h update + write out
        if (tid < 128) {
            int u = tid;
            float gi = sigf(gS[u]);
            float gf = sigf(gS[128 + u]);
            float gc = sigf(gS[256 + u]);
            float cn = gf * cS[u] + gi * tanh_(gc);
            cS[u] = cn;
            float hn = sigf(opC[tt * 128 + u]) * tanh_(cn);
            hS[u] = hn;
            outp[((size_t)bp * TT + t) * 128 + u] = hn;
        }
        __syncthreads();
    }
}

// ===== Verified fallback (unchanged): chunk-phase kernel =====
template <bool WS>
__global__ __launch_bounds__(512, 1) void tkan(
    const float* __restrict__ xg, const float* __restrict__ Wk,
    const float* __restrict__ Wr, const float* __restrict__ bias,
    const float* __restrict__ Wx, const float* __restrict__ Wh,
    const float* __restrict__ stk, const float* __restrict__ Dw,
    const float* __restrict__ Db, const float* __restrict__ Aw,
    const float* __restrict__ Ab, const __half* __restrict__ wt,
    float* __restrict__ outp) {
    const int bp = blockIdx.x, tid = threadIdx.x;

    __shared__ float xC[4][TC][128];
    __shared__ __half gxL[TC][384];
    __shared__ __half axL[TC][384];
    __shared__ float hS[128], cS[128], tcS[128];
    __shared__ float sS[384], aS[384], pS[384], gS[384];
    __shared__ float part1[384][4], part2[192][4], part3[256][4];
    __shared__ float biasL[384], stkj[3][2][128], DbL[3][128], AbL[128];
    __shared__ float dummy[WS ? 4 : 4096];

    if (tid < 128) { hS[tid] = 0.f; cS[tid] = 0.f; AbL[tid] = Ab[tid]; }
    if (tid >= 128 && tid < 512) {
        int q = tid - 128;
        sS[q] = 0.f;
        biasL[q] = bias[q];
    }
    {
        int j = tid >> 7, o = tid & 127;
        if (j < 3) {
            int nj = (3 * bp + j) >> 6;
            stkj[j][0][o] = stk[nj * 256 + o];
            stkj[j][1][o] = stk[nj * 256 + 128 + o];
            DbL[j][o] = Db[nj * 128 + o];
        }
    }
    if (bias[0] > 1e30f) { dummy[tid & 3] = 1.f; }
    __syncthreads();

    const float4* Wk4 = (const float4*)Wk;
    const float4* Wx4 = (const float4*)Wx;
    const void* wWr = WS ? (const void*)(wt)          : (const void*)Wr;
    const void* wWh = WS ? (const void*)(wt + 49152)  : (const void*)Wh;
    const void* wDw = WS ? (const void*)(wt + 98304)  : (const void*)Dw;
    const void* wAw = WS ? (const void*)(wt + 147456) : (const void*)Aw;

    for (int t = 0; t < TT; ++t) {
        int tt = t & (TC - 1);
        if (tt == 0) {
            for (int f = tid; f < 4096; f += 512) {
                int v_ = f >> 10, ti = (f >> 5) & 31, kq = f & 31;
                int row = (v_ == 0) ? bp : ((3 * bp + (v_ - 1)) & 63);
                float4 w = ((const float4*)(xg + ((size_t)row * TT + t + ti) * 128))[kq];
                float* d = &xC[v_][ti][kq * 4];
                d[0] = w.x; d[1] = w.y; d[2] = w.z; d[3] = w.w;
            }
            __syncthreads();
            for (int ct = tid; ct < TC * 192; ct += 512) {
                int ti = ct / 192, r = ct % 192;
                float4 acc = {0.f, 0.f, 0.f, 0.f};
                if (r < 96) {
                    const float* v = xC[0][ti];
#pragma unroll 8
                    for (int k = 0; k < 128; ++k) {
                        float4 w = Wk4[k * 96 + r];
                        float xv = v[k];
                        acc.x += w.x * xv; acc.y += w.y * xv;
                        acc.z += w.z * xv; acc.w += w.w * xv;
                    }
                    int qout = r;
                    ((__half2*)&gxL[ti][0])[2 * qout] = __floats2half2_rn(acc.x, acc.y);
                    ((__half2*)&gxL[ti][0])[2 * qout + 1] = __floats2half2_rn(acc.z, acc.w);
                } else {
                    int jq = r - 96, j = jq >> 5, qi = jq & 31;
                    int nj = (3 * bp + j) >> 6;
                    const float* v = xC[1 + j][ti];
#pragma unroll 8
                    for (int k = 0; k < 128; ++k) {
                        float4 w = Wx4[nj * 4096 + k * 32 + qi];
                        float xv = v[k];
                        acc.x += w.x * xv; acc.y += w.y * xv;
                        acc.z += w.z * xv; acc.w += w.w * xv;
                    }
                    int cq = j * 32 + qi;
                    ((__half2*)&axL[ti][0])[2 * cq] = __floats2half2_rn(acc.x, acc.y);
                    ((__half2*)&axL[ti][0])[2 * cq + 1] = __floats2half2_rn(acc.z, acc.w);
                }
            }
            __syncthreads();
        }

        if (tid < 384) {
            float4 acc = {0.f, 0.f, 0.f, 0.f};
            if (tid < 192) {
                int q = tid % 96, ks = tid / 96;
                dotq<WS>(wWr, q, 96, hS, ks * 64, 64, acc);
            } else {
                int t2 = tid - 192;
                int jq = t2 % 96, ks = t2 / 96;
                int j = jq >> 5, qi = jq & 31;
                int nj = (3 * bp + j) >> 6;
                dotq<WS>(wWh, nj * 4096 + qi, 32, sS + j * 128, ks * 64, 64, acc);
            }
            *(float4*)&part1[tid][0] = acc;
        }
        __syncthreads();

        if (tid < 192) {
            if (tid < 96) {
                int q = tid;
                float4 a0 = *(float4*)&part1[q][0];
                float4 a1 = *(float4*)&part1[q + 96][0];
                float2 g0 = h2f2(((const u32*)&gxL[tt][0])[2 * q]);
                float2 g1 = h2f2(((const u32*)&gxL[tt][0])[2 * q + 1]);
                float4 r;
                r.x = a0.x + a1.x + g0.x + biasL[4 * q];
                r.y = a0.y + a1.y + g0.y + biasL[4 * q + 1];
                r.z = a0.z + a1.z + g1.x + biasL[4 * q + 2];
                r.w = a0.w + a1.w + g1.y + biasL[4 * q + 3];
                *(float4*)&gS[4 * q] = r;
            } else {
                int cq = tid - 96;
                float4 a0 = *(float4*)&part1[192 + cq][0];
                float4 a1 = *(float4*)&part1[288 + cq][0];
                float2 g0 = h2f2(((const u32*)&axL[tt][0])[2 * cq]);
                float2 g1 = h2f2(((const u32*)&axL[tt][0])[2 * cq + 1]);
                float4 r;
                r.x = a0.x + a1.x + g0.x;
                r.y = a0.y + a1.y + g0.y;
                r.z = a0.z + a1.z + g1.x;
                r.w = a0.w + a1.w + g1.y;
                *(float4*)&aS[4 * cq] = r;
            }
        }
        __syncthreads();

        if (tid < 192) {
            int q = tid % 96, ks = tid / 96;
            int j = q >> 5, qi = q & 31;
            int nj = (3 * bp + j) >> 6;
            float4 acc = {0.f, 0.f, 0.f, 0.f};
            dotq<WS>(wDw, nj * 4096 + qi, 32, aS + j * 128, ks * 64, 64, acc);
            *(float4*)&part2[tid][0] = acc;
        } else if (tid >= 384) {
            int u = tid - 384;
            float gi = sigf(gS[u]);
            float gf = sigf(gS[128 + u]);
            float gc = sigf(gS[256 + u]);
            float cn = gf * cS[u] + gi * tanh_(gc);
            cS[u] = cn;
            tcS[u] = tanh_(cn);
        }
        __syncthreads();

        if (tid < 96) {
            int j = tid >> 5, o = (tid & 31) * 4;
            float4 a0 = *(float4*)&part2[tid][0];
            float4 a1 = *(float4*)&part2[tid + 96][0];
            float4 r;
            r.x = fmaxf(a0.x + a1.x + DbL[j][o], 0.f);
            r.y = fmaxf(a0.y + a1.y + DbL[j][o + 1], 0.f);
            r.z = fmaxf(a0.z + a1.z + DbL[j][o + 2], 0.f);
            r.w = fmaxf(a0.w + a1.w + DbL[j][o + 3], 0.f);
            *(float4*)&pS[4 * tid] = r;
        }
        __syncthreads();

        if (tid < 256) {
            int q = tid & 31, ks = tid >> 5;
            float4 acc = {0.f, 0.f, 0.f, 0.f};
            dotq<WS>(wAw, q, 32, pS, ks * 48, 48, acc);
            *(float4*)&part3[tid][0] = acc;
        } else if (tid < 384) {
            int e = tid - 256;
#pragma unroll
            for (int j = 0; j < 3; ++j) {
                int q = j * 128 + e;
                sS[q] = stkj[j][0][e] * pS[q] + stkj[j][1][e] * sS[q];
            }
        }
        __syncthreads();

        if (tid < 128) {
            int u = tid;
            float y = AbL[u];
#pragma unroll
            for (int ks = 0; ks < 8; ++ks) y += part3[ks * 32 + (u >> 2)][u & 3];
            float hn = sigf(y) * tcS[u];
            hS[u] = hn;
            outp[((size_t)bp * TT + t) * 128 + u] = hn;
        }
        __syncthreads();
    }
}

extern "C" void kernel_launch(void* const* d_in, const int* in_sizes, int n_in,
                              void* d_out, int out_size, void* d_ws, size_t ws_size,
                              hipStream_t stream) {
    const float* x    = (const float*)d_in[0];
    const float* Wk   = (const float*)d_in[1];
    const float* Wr   = (const float*)d_in[2];
    const float* bias = (const float*)d_in[3];
    const float* Wx   = (const float*)d_in[4];
    const float* Wh   = (const float*)d_in[5];
    const float* stk  = (const float*)d_in[6];
    const float* Dw   = (const float*)d_in[7];
    const float* Db   = (const float*)d_in[8];
    const float* Aw   = (const float*)d_in[9];
    const float* Ab   = (const float*)d_in[10];
    float* outp = (float*)d_out;

    const size_t needNew = (size_t)2 * BB * TT * 384 * sizeof(__half);  // 201,326,592
    const size_t needW   = 196608 * sizeof(__half);                     // fp16 weights
    if (ws_size >= needNew) {
        uint2* gxb = (uint2*)d_ws;
        uint2* axb = gxb + (size_t)BB * TT * 96;
        gax_pre2<<<dim3(BB, 64), dim3(384), 0, stream>>>(x, Wk, Wx, gxb, axb);
        subrec<<<dim3(BB), dim3(512), 0, stream>>>(Wh, Dw, stk, Db, axb);
        aggmm<<<dim3(BB, 16), dim3(256), 0, stream>>>(Aw, Ab, axb);
        gaterec<<<dim3(BB), dim3(512), 0, stream>>>(Wr, bias, gxb, axb, outp);
    } else if (ws_size >= needW) {
        __half* wt = (__half*)d_ws;
        convert_w<<<dim3(384), dim3(512), 0, stream>>>(Wr, Wh, Dw, Aw, wt);
        tkan<true><<<dim3(BB), dim3(512), 0, stream>>>(
            x, Wk, Wr, bias, Wx, Wh, stk, Dw, Db, Aw, Ab, wt, outp);
    } else {
        tkan<false><<<dim3(BB), dim3(512), 0, stream>>>(
            x, Wk, Wr, bias, Wx, Wh, stk, Dw, Db, Aw, Ab, (const __half*)nullptr,
            outp);
    }
}

// Round 8
// 7002.535 us; speedup vs baseline: 2.0159x; 1.2849x over previous
//
#include <hip/hip_runtime.h>
#include <hip/hip_fp16.h>

// TKANCell B=64,T=2048,D=128,U=128,NS=3 — fp32 in/out.
// 64 independent chains (tf.reshape routes sub-row r=3b'+j to batch b'=r/3).
// R10 (3rd resubmit; R11-R13 bench slots lost to GPU acquisition timeouts):
// R9 counters: subrec 4.55ms, gaterec ~3.4ms, both latency-bound at 64
// blocks (43% VALU on active CUs). The 3 sub-layers are mutually independent
// (s[j] couples only to itself) -> subrec3 runs 192 blocks (chain x j), 8
// waves each owning a K-slice of 16, s/agg in lane registers moved by __shfl
// (no shfl_xor trees, no wave-sync LDS). gaterec3 flattened the same way:
// per-lane col-pair dots on packed-fp16 u32 weights, K-half over 6 waves,
// c-state in a register. 2 barriers/step each (the serial minimum).

#define TT 2048
#define BB 64
#define TC 32

typedef unsigned int u32;

__device__ __forceinline__ float sigf(float x) { return 1.f / (1.f + __expf(-x)); }
__device__ __forceinline__ float tanh_(float x) { return 2.f / (1.f + __expf(-2.f * x)) - 1.f; }
__device__ __forceinline__ float2 h2f2(u32 u) {
    __half2 h = *(__half2*)&u;
    return __half22float2(h);
}

__device__ __forceinline__ void fma4(float4& acc, uint2 w, float xv) {
    float2 lo = h2f2(w.x), hi = h2f2(w.y);
    acc.x += lo.x * xv; acc.y += lo.y * xv;
    acc.z += hi.x * xv; acc.w += hi.y * xv;
}

// legacy dot for fallback kernel
template <bool WS>
__device__ __forceinline__ void dotq(const void* W, int idxBase, int stride,
                                     const float* __restrict__ v, int k0, int kn,
                                     float4& acc) {
    if (WS) {
        const uint2* Wp = (const uint2*)W;
#pragma unroll 8
        for (int k = k0; k < k0 + kn; ++k) {
            uint2 w = Wp[idxBase + k * stride];
            float2 lo = h2f2(w.x), hi = h2f2(w.y);
            float xv = v[k];
            acc.x += lo.x * xv; acc.y += lo.y * xv;
            acc.z += hi.x * xv; acc.w += hi.y * xv;
        }
    } else {
        const float4* Wp = (const float4*)W;
#pragma unroll 8
        for (int k = k0; k < k0 + kn; ++k) {
            float4 w = Wp[idxBase + k * stride];
            float xv = v[k];
            acc.x += w.x * xv; acc.y += w.y * xv;
            acc.z += w.z * xv; acc.w += w.w * xv;
        }
    }
}

// fp16 copy of Wr|Wh|Dw|Aw (fallback tier only).
__global__ __launch_bounds__(512) void convert_w(
    const float* __restrict__ Wr, const float* __restrict__ Wh,
    const float* __restrict__ Dw, const float* __restrict__ Aw,
    __half* __restrict__ dst) {
    int g = blockIdx.x * 512 + threadIdx.x;  // 0..196607
    int seg = g / 49152, idx = g % 49152;
    const float* src = (seg == 0) ? Wr : (seg == 1) ? Wh : (seg == 2) ? Dw : Aw;
    dst[g] = __float2half(src[idx]);
}

// ===== pre-pass: gx[bp][t][96quads] = x@Wk ; ax[bp][t][96quads] = x@Wx.
__global__ __launch_bounds__(384, 3) void gax_pre2(
    const float* __restrict__ xg, const float* __restrict__ Wk,
    const float* __restrict__ Wx, uint2* __restrict__ gxb,
    uint2* __restrict__ axb) {
    const int bp = blockIdx.x, tc = blockIdx.y, tid = threadIdx.x;
    const int t0 = tc * 32;
    __shared__ __align__(16) float xCt[4][128][32];  // 64KB, [v][k][ti]

    for (int f = tid; f < 4096; f += 384) {
        int v_ = f >> 10, ti = (f >> 5) & 31, kq = f & 31;
        int row = (v_ == 0) ? bp : ((3 * bp + (v_ - 1)) & 63);
        float4 w = ((const float4*)(xg + ((size_t)row * TT + t0 + ti) * 128))[kq];
        xCt[v_][4 * kq + 0][ti] = w.x;
        xCt[v_][4 * kq + 1][ti] = w.y;
        xCt[v_][4 * kq + 2][ti] = w.z;
        xCt[v_][4 * kq + 3][ti] = w.w;
    }
    __syncthreads();

    const float4* Wk4 = (const float4*)Wk;
    const float4* Wx4 = (const float4*)Wx;

    for (int task = tid; task < 768; task += 384) {
        int grp = task / 192, r = task % 192;
        int ti0 = grp * 8;
        const float4* Wp;
        int base, stride, v;
        if (r < 96) {
            Wp = Wk4; base = r; stride = 96; v = 0;
        } else {
            int jq = r - 96, j = jq >> 5, qi = jq & 31;
            int nj = (3 * bp + j) >> 6;
            Wp = Wx4; base = nj * 4096 + qi; stride = 32; v = 1 + j;
        }
        float4 acc[8];
#pragma unroll
        for (int i = 0; i < 8; ++i) acc[i] = make_float4(0.f, 0.f, 0.f, 0.f);
#pragma unroll 4
        for (int k = 0; k < 128; ++k) {
            float4 w = Wp[base + k * stride];
            float4 xa = *(const float4*)&xCt[v][k][ti0];
            float4 xb = *(const float4*)&xCt[v][k][ti0 + 4];
#pragma unroll
            for (int i = 0; i < 4; ++i) {
                float xv = (&xa.x)[i];
                acc[i].x += w.x * xv; acc[i].y += w.y * xv;
                acc[i].z += w.z * xv; acc[i].w += w.w * xv;
            }
#pragma unroll
            for (int i = 0; i < 4; ++i) {
                float xv = (&xb.x)[i];
                acc[4 + i].x += w.x * xv; acc[4 + i].y += w.y * xv;
                acc[4 + i].z += w.z * xv; acc[4 + i].w += w.w * xv;
            }
        }
#pragma unroll
        for (int i = 0; i < 8; ++i) {
            size_t rowo = ((size_t)bp * TT + (size_t)(t0 + ti0 + i)) * 96;
            __half2 lo = __floats2half2_rn(acc[i].x, acc[i].y);
            __half2 hi = __floats2half2_rn(acc[i].z, acc[i].w);
            uint2 pk = make_uint2(*(u32*)&lo, *(u32*)&hi);
            if (r < 96) gxb[rowo + r] = pk;
            else        axb[rowo + (r - 96)] = pk;
        }
    }
}

// ===== subrec3: s-recurrence for ONE (chain, sub) pair per block (192 blks).
// 8 waves x K-slice of 16; s/agg in lane registers via __shfl; partial sums
// cross waves through part1/part2 + the 2 per-step barriers.
__global__ __launch_bounds__(512) void subrec3(
    const float* __restrict__ Wh, const float* __restrict__ Dw,
    const float* __restrict__ stk, const float* __restrict__ Db,
    uint2* __restrict__ axp) {
    const int bp = blockIdx.x, j = blockIdx.y, tid = threadIdx.x;
    const int w = tid >> 6, l = tid & 63, lr = l & 15;
    const int nj = (3 * bp + j) >> 6;

    __shared__ u32 WhW[8192];                    // [k][colpair] 32KB
    __shared__ u32 DwW[8192];                    // 32KB
    __shared__ __align__(16) float2 part1[512];  // [w][cp] 4KB
    __shared__ __align__(16) float2 part2[512];  // 4KB
    __shared__ __align__(16) __half axH[1024];   // [8][128] 2KB
    __shared__ __align__(16) __half pH[1024];    // 2KB
    __shared__ float stkhL[128], stkxL[128], DbLw[128];

    for (int i = tid; i < 8192; i += 512) {
        float2 a = ((const float2*)Wh)[(size_t)nj * 8192 + i];
        float2 b = ((const float2*)Dw)[(size_t)nj * 8192 + i];
        __half2 ah = __floats2half2_rn(a.x, a.y);
        __half2 bh = __floats2half2_rn(b.x, b.y);
        WhW[i] = *(u32*)&ah;
        DwW[i] = *(u32*)&bh;
    }
    if (tid < 128) {
        stkhL[tid] = stk[nj * 256 + tid];
        stkxL[tid] = stk[nj * 256 + 128 + tid];
        DbLw[tid] = Db[nj * 128 + tid];
    }
    float s_reg = 0.f;  // lane holds s[16w + lr] (4 redundant copies per value)
    uint2* rowB = axp + (size_t)bp * TT * 96 + 32 * j;
    __syncthreads();

    const u32* WhB = WhW + (16 * w) * 64 + l;
    const u32* DwB = DwW + (16 * w) * 64 + l;

    for (int t = 0; t < TT; ++t) {
        int tt = t & 7;
        if (tt == 0) {
            __syncthreads();  // pH writes (post-bar2 of t-1) visible
            if (t) {          // flush p chunk [t-8, t)
                uint2* dst = rowB + (size_t)(t - 8) * 96;
                for (int i = tid; i < 256; i += 512)
                    dst[(size_t)(i >> 5) * 96 + (i & 31)] = ((uint2*)pH)[i];
            }
            const uint2* src = rowB + (size_t)t * 96;
            for (int i = tid; i < 256; i += 512)
                ((uint2*)axH)[i] = src[(size_t)(i >> 5) * 96 + (i & 31)];
            __syncthreads();
        }

        // ph1: partial agg = s@Wh over k in [16w, 16w+16)
        {
            float2 a0 = {0.f, 0.f}, a1 = {0.f, 0.f};
#pragma unroll
            for (int k2 = 0; k2 < 8; ++k2) {
                float sv0 = __shfl(s_reg, 2 * k2, 64);
                float sv1 = __shfl(s_reg, 2 * k2 + 1, 64);
                float2 w0 = h2f2(WhB[(2 * k2) * 64]);
                float2 w1 = h2f2(WhB[(2 * k2 + 1) * 64]);
                a0.x += w0.x * sv0; a0.y += w0.y * sv0;
                a1.x += w1.x * sv1; a1.y += w1.y * sv1;
            }
            part1[w * 64 + l] = make_float2(a0.x + a1.x, a0.y + a1.y);
        }
        __syncthreads();

        // reduce agg col c=16w+lr (all lanes, x4 redundant) + ph2 partial dot
        float a_reg;
        {
            int c = 16 * w + lr;
            const float* p1 = (const float*)part1;
            float sum = p1[c];
#pragma unroll
            for (int p = 1; p < 8; ++p) sum += p1[p * 128 + c];
            a_reg = sum + __half2float(axH[tt * 128 + c]);
        }
        {
            float2 a0 = {0.f, 0.f}, a1 = {0.f, 0.f};
#pragma unroll
            for (int k2 = 0; k2 < 8; ++k2) {
                float av0 = __shfl(a_reg, 2 * k2, 64);
                float av1 = __shfl(a_reg, 2 * k2 + 1, 64);
                float2 w0 = h2f2(DwB[(2 * k2) * 64]);
                float2 w1 = h2f2(DwB[(2 * k2 + 1) * 64]);
                a0.x += w0.x * av0; a0.y += w0.y * av0;
                a1.x += w1.x * av1; a1.y += w1.y * av1;
            }
            part2[w * 64 + l] = make_float2(a0.x + a1.x, a0.y + a1.y);
        }
        __syncthreads();

        // reduce p col c, update s (register), stash p fp16
        {
            int c = 16 * w + lr;
            const float* p2 = (const float*)part2;
            float sum = p2[c];
#pragma unroll
            for (int p = 1; p < 8; ++p) sum += p2[p * 128 + c];
            float pv = fmaxf(sum + DbLw[c], 0.f);
            s_reg = stkhL[c] * pv + stkxL[c] * s_reg;
            if (l < 16) pH[tt * 128 + c] = __float2half(pv);
        }
    }
    __syncthreads();
    {
        uint2* dst = rowB + (size_t)(TT - 8) * 96;
        for (int i = tid; i < 256; i += 512)
            dst[(size_t)(i >> 5) * 96 + (i & 31)] = ((uint2*)pH)[i];
    }
}

// ===== aggmm: o_pre = p@Aw + Ab (fp32), written in place over p rows.
__global__ __launch_bounds__(256) void aggmm(
    const float* __restrict__ Aw, const float* __restrict__ Ab,
    uint2* __restrict__ axp) {
    const int bp = blockIdx.x, tg = blockIdx.y, tid = threadIdx.x;
    __shared__ uint2 AwL[12288];                 // [k*32+q] 96KB
    __shared__ __align__(16) float pT[32][384];  // 48KB
    __shared__ float AbL[128];

    for (int i = tid; i < 12288; i += 256) {
        float4 a = ((const float4*)Aw)[i];
        __half2 lo = __floats2half2_rn(a.x, a.y), hi = __floats2half2_rn(a.z, a.w);
        AwL[i] = make_uint2(*(u32*)&lo, *(u32*)&hi);
    }
    if (tid < 128) AbL[tid] = Ab[tid];

    uint2* rowBase = axp + (size_t)bp * TT * 96;
    for (int sc = 0; sc < 4; ++sc) {
        int t0 = tg * 128 + sc * 32;
        __syncthreads();
        for (int i = tid; i < 3072; i += 256) {
            int trow = i / 96, q = i % 96;
            uint2 v = rowBase[(size_t)(t0 + trow) * 96 + q];
            float2 lo = h2f2(v.x), hi = h2f2(v.y);
            pT[trow][4 * q] = lo.x;
            pT[trow][4 * q + 1] = lo.y;
            pT[trow][4 * q + 2] = hi.x;
            pT[trow][4 * q + 3] = hi.y;
        }
        __syncthreads();
#pragma unroll
        for (int it = 0; it < 4; ++it) {
            int task = tid + 256 * it;
            int trow = task >> 5, q = task & 31;
            const float* pv = &pT[trow][0];
            float4 acc = {0.f, 0.f, 0.f, 0.f};
#pragma unroll 4
            for (int k = 0; k < 384; k += 4) {
                float4 vv = *(const float4*)&pv[k];
                fma4(acc, AwL[(k + 0) * 32 + q], vv.x);
                fma4(acc, AwL[(k + 1) * 32 + q], vv.y);
                fma4(acc, AwL[(k + 2) * 32 + q], vv.z);
                fma4(acc, AwL[(k + 3) * 32 + q], vv.w);
            }
            float* dst = (float*)(rowBase + (size_t)(t0 + trow) * 96);
            float4 r;
            r.x = acc.x + AbL[4 * q];
            r.y = acc.y + AbL[4 * q + 1];
            r.z = acc.z + AbL[4 * q + 2];
            r.w = acc.w + AbL[4 * q + 3];
            *(float4*)(dst + 4 * q) = r;
        }
    }
}

// ===== gaterec3: gate recurrence; per-lane col-pair dots, K-half over 6
// waves, c-state in register, 2 barriers/step.
__global__ __launch_bounds__(512) void gaterec3(
    const float* __restrict__ Wr, const float* __restrict__ bias,
    const uint2* __restrict__ gxb, const uint2* __restrict__ axp,
    float* __restrict__ outp) {
    const int bp = blockIdx.x, tid = threadIdx.x;
    const int w = tid >> 6, l = tid & 63;

    __shared__ u32 WrW[24576];                   // [k][cp(192)] 96KB
    __shared__ __align__(16) uint2 gxC[768];     // 6KB
    __shared__ __align__(16) float opC[1024];    // 4KB
    __shared__ __align__(16) float2 partg[384];  // [kh][cp] 3KB
    __shared__ __align__(16) float hS[128];
    __shared__ float biasL[384];

    for (int i = tid; i < 24576; i += 512) {
        float2 a = ((const float2*)Wr)[i];  // [k][384] -> float2 idx == k*192+cp
        __half2 ah = __floats2half2_rn(a.x, a.y);
        WrW[i] = *(u32*)&ah;
    }
    if (tid < 384) biasL[tid] = bias[tid];
    if (tid < 128) hS[tid] = 0.f;
    float c_reg = 0.f;  // threads 0-127 own c[u]
    const uint2* gxRow = gxb + (size_t)bp * TT * 96;
    const float* opRow = (const float*)(axp + (size_t)bp * TT * 96);
    __syncthreads();

    const int kh = (w >= 3) ? 1 : 0;
    const int cp = (w - 3 * kh) * 64 + l;        // 0..191 (waves 0-5)
    const u32* WrB = WrW + (64 * kh) * 192 + cp;

    for (int t = 0; t < TT; ++t) {
        int tt = t & 7;
        if (tt == 0) {
            // prior readers of gxC/opC finished before bar2(t-1); writes here
            // become visible to reduce() via bar1.
            for (int i = tid; i < 768; i += 512)
                gxC[i] = gxRow[(size_t)t * 96 + i];
            for (int i = tid; i < 256; i += 512) {
                int row = i >> 5, f4 = i & 31;
                *(float4*)&opC[row * 128 + 4 * f4] =
                    ((const float4*)(opRow + (size_t)(t + row) * 192))[f4];
            }
        }

        // dot: waves 0-5, per-lane col-pair, K-half each
        if (w < 6) {
            float2 a0 = {0.f, 0.f}, a1 = {0.f, 0.f};
#pragma unroll
            for (int k2 = 0; k2 < 32; ++k2) {
                float h0 = hS[64 * kh + 2 * k2];
                float h1 = hS[64 * kh + 2 * k2 + 1];
                float2 w0 = h2f2(WrB[(2 * k2) * 192]);
                float2 w1 = h2f2(WrB[(2 * k2 + 1) * 192]);
                a0.x += w0.x * h0; a0.y += w0.y * h0;
                a1.x += w1.x * h1; a1.y += w1.y * h1;
            }
            partg[kh * 192 + cp] = make_float2(a0.x + a1.x, a0.y + a1.y);
        }
        __syncthreads();

        // reduce + pointwise on threads 0-127
        if (tid < 128) {
            int u = tid;
            const float* pg = (const float*)partg;
            const __half* gxh = (const __half*)gxC;
            float gi = pg[u] + pg[384 + u]
                     + __half2float(gxh[tt * 384 + u]) + biasL[u];
            float gf = pg[128 + u] + pg[512 + u]
                     + __half2float(gxh[tt * 384 + 128 + u]) + biasL[128 + u];
            float gc = pg[256 + u] + pg[640 + u]
                     + __half2float(gxh[tt * 384 + 256 + u]) + biasL[256 + u];
            float si = sigf(gi), sf = sigf(gf), sc = sigf(gc);
            float cn = sf * c_reg + si * tanh_(sc);
            c_reg = cn;
            float hn = sigf(opC[tt * 128 + u]) * tanh_(cn);
            hS[u] = hn;
            outp[((size_t)bp * TT + t) * 128 + u] = hn;
        }
        __syncthreads();
    }
}

// ===== Verified fallback (unchanged): chunk-phase kernel =====
template <bool WS>
__global__ __launch_bounds__(512, 1) void tkan(
    const float* __restrict__ xg, const float* __restrict__ Wk,
    const float* __restrict__ Wr, const float* __restrict__ bias,
    const float* __restrict__ Wx, const float* __restrict__ Wh,
    const float* __restrict__ stk, const float* __restrict__ Dw,
    const float* __restrict__ Db, const float* __restrict__ Aw,
    const float* __restrict__ Ab, const __half* __restrict__ wt,
    float* __restrict__ outp) {
    const int bp = blockIdx.x, tid = threadIdx.x;

    __shared__ float xC[4][TC][128];
    __shared__ __half gxL[TC][384];
    __shared__ __half axL[TC][384];
    __shared__ float hS[128], cS[128], tcS[128];
    __shared__ float sS[384], aS[384], pS[384], gS[384];
    __shared__ float part1[384][4], part2[192][4], part3[256][4];
    __shared__ float biasL[384], stkj[3][2][128], DbL[3][128], AbL[128];
    __shared__ float dummy[WS ? 4 : 4096];

    if (tid < 128) { hS[tid] = 0.f; cS[tid] = 0.f; AbL[tid] = Ab[tid]; }
    if (tid >= 128 && tid < 512) {
        int q = tid - 128;
        sS[q] = 0.f;
        biasL[q] = bias[q];
    }
    {
        int j = tid >> 7, o = tid & 127;
        if (j < 3) {
            int nj = (3 * bp + j) >> 6;
            stkj[j][0][o] = stk[nj * 256 + o];
            stkj[j][1][o] = stk[nj * 256 + 128 + o];
            DbL[j][o] = Db[nj * 128 + o];
        }
    }
    if (bias[0] > 1e30f) { dummy[tid & 3] = 1.f; }
    __syncthreads();

    const float4* Wk4 = (const float4*)Wk;
    const float4* Wx4 = (const float4*)Wx;
    const void* wWr = WS ? (const void*)(wt)          : (const void*)Wr;
    const void* wWh = WS ? (const void*)(wt + 49152)  : (const void*)Wh;
    const void* wDw = WS ? (const void*)(wt + 98304)  : (const void*)Dw;
    const void* wAw = WS ? (const void*)(wt + 147456) : (const void*)Aw;

    for (int t = 0; t < TT; ++t) {
        int tt = t & (TC - 1);
        if (tt == 0) {
            for (int f = tid; f < 4096; f += 512) {
                int v_ = f >> 10, ti = (f >> 5) & 31, kq = f & 31;
                int row = (v_ == 0) ? bp : ((3 * bp + (v_ - 1)) & 63);
                float4 w = ((const float4*)(xg + ((size_t)row * TT + t + ti) * 128))[kq];
                float* d = &xC[v_][ti][kq * 4];
                d[0] = w.x; d[1] = w.y; d[2] = w.z; d[3] = w.w;
            }
            __syncthreads();
            for (int ct = tid; ct < TC * 192; ct += 512) {
                int ti = ct / 192, r = ct % 192;
                float4 acc = {0.f, 0.f, 0.f, 0.f};
                if (r < 96) {
                    const float* v = xC[0][ti];
#pragma unroll 8
                    for (int k = 0; k < 128; ++k) {
                        float4 w = Wk4[k * 96 + r];
                        float xv = v[k];
                        acc.x += w.x * xv; acc.y += w.y * xv;
                        acc.z += w.z * xv; acc.w += w.w * xv;
                    }
                    int qout = r;
                    ((__half2*)&gxL[ti][0])[2 * qout] = __floats2half2_rn(acc.x, acc.y);
                    ((__half2*)&gxL[ti][0])[2 * qout + 1] = __floats2half2_rn(acc.z, acc.w);
                } else {
                    int jq = r - 96, j = jq >> 5, qi = jq & 31;
                    int nj = (3 * bp + j) >> 6;
                    const float* v = xC[1 + j][ti];
#pragma unroll 8
                    for (int k = 0; k < 128; ++k) {
                        float4 w = Wx4[nj * 4096 + k * 32 + qi];
                        float xv = v[k];
                        acc.x += w.x * xv; acc.y += w.y * xv;
                        acc.z += w.z * xv; acc.w += w.w * xv;
                    }
                    int cq = j * 32 + qi;
                    ((__half2*)&axL[ti][0])[2 * cq] = __floats2half2_rn(acc.x, acc.y);
                    ((__half2*)&axL[ti][0])[2 * cq + 1] = __floats2half2_rn(acc.z, acc.w);
                }
            }
            __syncthreads();
        }

        if (tid < 384) {
            float4 acc = {0.f, 0.f, 0.f, 0.f};
            if (tid < 192) {
                int q = tid % 96, ks = tid / 96;
                dotq<WS>(wWr, q, 96, hS, ks * 64, 64, acc);
            } else {
                int t2 = tid - 192;
                int jq = t2 % 96, ks = t2 / 96;
                int j = jq >> 5, qi = jq & 31;
                int nj = (3 * bp + j) >> 6;
                dotq<WS>(wWh, nj * 4096 + qi, 32, sS + j * 128, ks * 64, 64, acc);
            }
            *(float4*)&part1[tid][0] = acc;
        }
        __syncthreads();

        if (tid < 192) {
            if (tid < 96) {
                int q = tid;
                float4 a0 = *(float4*)&part1[q][0];
                float4 a1 = *(float4*)&part1[q + 96][0];
                float2 g0 = h2f2(((const u32*)&gxL[tt][0])[2 * q]);
                float2 g1 = h2f2(((const u32*)&gxL[tt][0])[2 * q + 1]);
                float4 r;
                r.x = a0.x + a1.x + g0.x + biasL[4 * q];
                r.y = a0.y + a1.y + g0.y + biasL[4 * q + 1];
                r.z = a0.z + a1.z + g1.x + biasL[4 * q + 2];
                r.w = a0.w + a1.w + g1.y + biasL[4 * q + 3];
                *(float4*)&gS[4 * q] = r;
            } else {
                int cq = tid - 96;
                float4 a0 = *(float4*)&part1[192 + cq][0];
                float4 a1 = *(float4*)&part1[288 + cq][0];
                float2 g0 = h2f2(((const u32*)&axL[tt][0])[2 * cq]);
                float2 g1 = h2f2(((const u32*)&axL[tt][0])[2 * cq + 1]);
                float4 r;
                r.x = a0.x + a1.x + g0.x;
                r.y = a0.y + a1.y + g0.y;
                r.z = a0.z + a1.z + g1.x;
                r.w = a0.w + a1.w + g1.y;
                *(float4*)&aS[4 * cq] = r;
            }
        }
        __syncthreads();

        if (tid < 192) {
            int q = tid % 96, ks = tid / 96;
            int j = q >> 5, qi = q & 31;
            int nj = (3 * bp + j) >> 6;
            float4 acc = {0.f, 0.f, 0.f, 0.f};
            dotq<WS>(wDw, nj * 4096 + qi, 32, aS + j * 128, ks * 64, 64, acc);
            *(float4*)&part2[tid][0] = acc;
        } else if (tid >= 384) {
            int u = tid - 384;
            float gi = sigf(gS[u]);
            float gf = sigf(gS[128 + u]);
            float gc = sigf(gS[256 + u]);
            float cn = gf * cS[u] + gi * tanh_(gc);
            cS[u] = cn;
            tcS[u] = tanh_(cn);
        }
        __syncthreads();

        if (tid < 96) {
            int j = tid >> 5, o = (tid & 31) * 4;
            float4 a0 = *(float4*)&part2[tid][0];
            float4 a1 = *(float4*)&part2[tid + 96][0];
            float4 r;
            r.x = fmaxf(a0.x + a1.x + DbL[j][o], 0.f);
            r.y = fmaxf(a0.y + a1.y + DbL[j][o + 1], 0.f);
            r.z = fmaxf(a0.z + a1.z + DbL[j][o + 2], 0.f);
            r.w = fmaxf(a0.w + a1.w + DbL[j][o + 3], 0.f);
            *(float4*)&pS[4 * tid] = r;
        }
        __syncthreads();

        if (tid < 256) {
            int q = tid & 31, ks = tid >> 5;
            float4 acc = {0.f, 0.f, 0.f, 0.f};
            dotq<WS>(wAw, q, 32, pS, ks * 48, 48, acc);
            *(float4*)&part3[tid][0] = acc;
        } else if (tid < 384) {
            int e = tid - 256;
#pragma unroll
            for (int j = 0; j < 3; ++j) {
                int q = j * 128 + e;
                sS[q] = stkj[j][0][e] * pS[q] + stkj[j][1][e] * sS[q];
            }
        }
        __syncthreads();

        if (tid < 128) {
            int u = tid;
            float y = AbL[u];
#pragma unroll
            for (int ks = 0; ks < 8; ++ks) y += part3[ks * 32 + (u >> 2)][u & 3];
            float hn = sigf(y) * tcS[u];
            hS[u] = hn;
            outp[((size_t)bp * TT + t) * 128 + u] = hn;
        }
        __syncthreads();
    }
}

extern "C" void kernel_launch(void* const* d_in, const int* in_sizes, int n_in,
                              void* d_out, int out_size, void* d_ws, size_t ws_size,
                              hipStream_t stream) {
    const float* x    = (const float*)d_in[0];
    const float* Wk   = (const float*)d_in[1];
    const float* Wr   = (const float*)d_in[2];
    const float* bias = (const float*)d_in[3];
    const float* Wx   = (const float*)d_in[4];
    const float* Wh   = (const float*)d_in[5];
    const float* stk  = (const float*)d_in[6];
    const float* Dw   = (const float*)d_in[7];
    const float* Db   = (const float*)d_in[8];
    const float* Aw   = (const float*)d_in[9];
    const float* Ab   = (const float*)d_in[10];
    float* outp = (float*)d_out;

    const size_t needNew = (size_t)2 * BB * TT * 384 * sizeof(__half);  // 201,326,592
    const size_t needW   = 196608 * sizeof(__half);                     // fp16 weights
    if (ws_size >= needNew) {
        uint2* gxb = (uint2*)d_ws;
        uint2* axb = gxb + (size_t)BB * TT * 96;
        gax_pre2<<<dim3(BB, 64), dim3(384), 0, stream>>>(x, Wk, Wx, gxb, axb);
        subrec3<<<dim3(BB, 3), dim3(512), 0, stream>>>(Wh, Dw, stk, Db, axb);
        aggmm<<<dim3(BB, 16), dim3(256), 0, stream>>>(Aw, Ab, axb);
        gaterec3<<<dim3(BB), dim3(512), 0, stream>>>(Wr, bias, gxb, axb, outp);
    } else if (ws_size >= needW) {
        __half* wt = (__half*)d_ws;
        convert_w<<<dim3(384), dim3(512), 0, stream>>>(Wr, Wh, Dw, Aw, wt);
        tkan<true><<<dim3(BB), dim3(512), 0, stream>>>(
            x, Wk, Wr, bias, Wx, Wh, stk, Dw, Db, Aw, Ab, wt, outp);
    } else {
        tkan<false><<<dim3(BB), dim3(512), 0, stream>>>(
            x, Wk, Wr, bias, Wx, Wh, stk, Dw, Db, Aw, Ab, (const __half*)nullptr,
            outp);
    }
}

// Round 12
// 6772.519 us; speedup vs baseline: 2.0844x; 1.0340x over previous
//
#include <hip/hip_runtime.h>
#include <hip/hip_fp16.h>

// TKANCell B=64,T=2048,D=128,U=128,NS=3 — fp32 in/out.
// 64 independent chains (tf.reshape routes sub-row r=3b'+j to batch b'=r/3).
// R15 (2nd resubmit; R16/R17 bench slots lost to GPU acquisition timeouts):
// R14's gaterec4 FAILED (absmax 0.08, nondeterministic): readlane read
// lanes 48-63 whose h_lo/h_hi defs the compiler could sink under the l<48
// predicate -> undefined registers. Fix: h broadcast via wave-uniform LDS
// read hS[32w+kk] (single ds_read_b32 broadcast, no cross-lane dependency).
// Keeps the R14 gains: ds_read_b128 weight reads (8 fp16 cols/op), 4 dot
// waves K-chunk 32, waves 4-7 double-buffer staging of gx/o_pre chunks.
// subrec3 / aggmm / gax_pre2 / fallbacks unchanged (verified R10, 7.0ms).

#define TT 2048
#define BB 64
#define TC 32

typedef unsigned int u32;

__device__ __forceinline__ float sigf(float x) { return 1.f / (1.f + __expf(-x)); }
__device__ __forceinline__ float tanh_(float x) { return 2.f / (1.f + __expf(-2.f * x)) - 1.f; }
__device__ __forceinline__ float2 h2f2(u32 u) {
    __half2 h = *(__half2*)&u;
    return __half22float2(h);
}

__device__ __forceinline__ void fma4(float4& acc, uint2 w, float xv) {
    float2 lo = h2f2(w.x), hi = h2f2(w.y);
    acc.x += lo.x * xv; acc.y += lo.y * xv;
    acc.z += hi.x * xv; acc.w += hi.y * xv;
}

// legacy dot for fallback kernel
template <bool WS>
__device__ __forceinline__ void dotq(const void* W, int idxBase, int stride,
                                     const float* __restrict__ v, int k0, int kn,
                                     float4& acc) {
    if (WS) {
        const uint2* Wp = (const uint2*)W;
#pragma unroll 8
        for (int k = k0; k < k0 + kn; ++k) {
            uint2 w = Wp[idxBase + k * stride];
            float2 lo = h2f2(w.x), hi = h2f2(w.y);
            float xv = v[k];
            acc.x += lo.x * xv; acc.y += lo.y * xv;
            acc.z += hi.x * xv; acc.w += hi.y * xv;
        }
    } else {
        const float4* Wp = (const float4*)W;
#pragma unroll 8
        for (int k = k0; k < k0 + kn; ++k) {
            float4 w = Wp[idxBase + k * stride];
            float xv = v[k];
            acc.x += w.x * xv; acc.y += w.y * xv;
            acc.z += w.z * xv; acc.w += w.w * xv;
        }
    }
}

// fp16 copy of Wr|Wh|Dw|Aw (fallback tier only).
__global__ __launch_bounds__(512) void convert_w(
    const float* __restrict__ Wr, const float* __restrict__ Wh,
    const float* __restrict__ Dw, const float* __restrict__ Aw,
    __half* __restrict__ dst) {
    int g = blockIdx.x * 512 + threadIdx.x;  // 0..196607
    int seg = g / 49152, idx = g % 49152;
    const float* src = (seg == 0) ? Wr : (seg == 1) ? Wh : (seg == 2) ? Dw : Aw;
    dst[g] = __float2half(src[idx]);
}

// ===== pre-pass: gx[bp][t][96quads] = x@Wk ; ax[bp][t][96quads] = x@Wx.
__global__ __launch_bounds__(384, 3) void gax_pre2(
    const float* __restrict__ xg, const float* __restrict__ Wk,
    const float* __restrict__ Wx, uint2* __restrict__ gxb,
    uint2* __restrict__ axb) {
    const int bp = blockIdx.x, tc = blockIdx.y, tid = threadIdx.x;
    const int t0 = tc * 32;
    __shared__ __align__(16) float xCt[4][128][32];  // 64KB, [v][k][ti]

    for (int f = tid; f < 4096; f += 384) {
        int v_ = f >> 10, ti = (f >> 5) & 31, kq = f & 31;
        int row = (v_ == 0) ? bp : ((3 * bp + (v_ - 1)) & 63);
        float4 w = ((const float4*)(xg + ((size_t)row * TT + t0 + ti) * 128))[kq];
        xCt[v_][4 * kq + 0][ti] = w.x;
        xCt[v_][4 * kq + 1][ti] = w.y;
        xCt[v_][4 * kq + 2][ti] = w.z;
        xCt[v_][4 * kq + 3][ti] = w.w;
    }
    __syncthreads();

    const float4* Wk4 = (const float4*)Wk;
    const float4* Wx4 = (const float4*)Wx;

    for (int task = tid; task < 768; task += 384) {
        int grp = task / 192, r = task % 192;
        int ti0 = grp * 8;
        const float4* Wp;
        int base, stride, v;
        if (r < 96) {
            Wp = Wk4; base = r; stride = 96; v = 0;
        } else {
            int jq = r - 96, j = jq >> 5, qi = jq & 31;
            int nj = (3 * bp + j) >> 6;
            Wp = Wx4; base = nj * 4096 + qi; stride = 32; v = 1 + j;
        }
        float4 acc[8];
#pragma unroll
        for (int i = 0; i < 8; ++i) acc[i] = make_float4(0.f, 0.f, 0.f, 0.f);
#pragma unroll 4
        for (int k = 0; k < 128; ++k) {
            float4 w = Wp[base + k * stride];
            float4 xa = *(const float4*)&xCt[v][k][ti0];
            float4 xb = *(const float4*)&xCt[v][k][ti0 + 4];
#pragma unroll
            for (int i = 0; i < 4; ++i) {
                float xv = (&xa.x)[i];
                acc[i].x += w.x * xv; acc[i].y += w.y * xv;
                acc[i].z += w.z * xv; acc[i].w += w.w * xv;
            }
#pragma unroll
            for (int i = 0; i < 4; ++i) {
                float xv = (&xb.x)[i];
                acc[4 + i].x += w.x * xv; acc[4 + i].y += w.y * xv;
                acc[4 + i].z += w.z * xv; acc[4 + i].w += w.w * xv;
            }
        }
#pragma unroll
        for (int i = 0; i < 8; ++i) {
            size_t rowo = ((size_t)bp * TT + (size_t)(t0 + ti0 + i)) * 96;
            __half2 lo = __floats2half2_rn(acc[i].x, acc[i].y);
            __half2 hi = __floats2half2_rn(acc[i].z, acc[i].w);
            uint2 pk = make_uint2(*(u32*)&lo, *(u32*)&hi);
            if (r < 96) gxb[rowo + r] = pk;
            else        axb[rowo + (r - 96)] = pk;
        }
    }
}

// ===== subrec3 (verified R10): s-recurrence, 192 blocks =====
__global__ __launch_bounds__(512) void subrec3(
    const float* __restrict__ Wh, const float* __restrict__ Dw,
    const float* __restrict__ stk, const float* __restrict__ Db,
    uint2* __restrict__ axp) {
    const int bp = blockIdx.x, j = blockIdx.y, tid = threadIdx.x;
    const int w = tid >> 6, l = tid & 63, lr = l & 15;
    const int nj = (3 * bp + j) >> 6;

    __shared__ u32 WhW[8192];                    // [k][colpair] 32KB
    __shared__ u32 DwW[8192];                    // 32KB
    __shared__ __align__(16) float2 part1[512];  // [w][cp] 4KB
    __shared__ __align__(16) float2 part2[512];  // 4KB
    __shared__ __align__(16) __half axH[1024];   // [8][128] 2KB
    __shared__ __align__(16) __half pH[1024];    // 2KB
    __shared__ float stkhL[128], stkxL[128], DbLw[128];

    for (int i = tid; i < 8192; i += 512) {
        float2 a = ((const float2*)Wh)[(size_t)nj * 8192 + i];
        float2 b = ((const float2*)Dw)[(size_t)nj * 8192 + i];
        __half2 ah = __floats2half2_rn(a.x, a.y);
        __half2 bh = __floats2half2_rn(b.x, b.y);
        WhW[i] = *(u32*)&ah;
        DwW[i] = *(u32*)&bh;
    }
    if (tid < 128) {
        stkhL[tid] = stk[nj * 256 + tid];
        stkxL[tid] = stk[nj * 256 + 128 + tid];
        DbLw[tid] = Db[nj * 128 + tid];
    }
    float s_reg = 0.f;
    uint2* rowB = axp + (size_t)bp * TT * 96 + 32 * j;
    __syncthreads();

    const u32* WhB = WhW + (16 * w) * 64 + l;
    const u32* DwB = DwW + (16 * w) * 64 + l;

    for (int t = 0; t < TT; ++t) {
        int tt = t & 7;
        if (tt == 0) {
            __syncthreads();
            if (t) {
                uint2* dst = rowB + (size_t)(t - 8) * 96;
                for (int i = tid; i < 256; i += 512)
                    dst[(size_t)(i >> 5) * 96 + (i & 31)] = ((uint2*)pH)[i];
            }
            const uint2* src = rowB + (size_t)t * 96;
            for (int i = tid; i < 256; i += 512)
                ((uint2*)axH)[i] = src[(size_t)(i >> 5) * 96 + (i & 31)];
            __syncthreads();
        }

        {
            float2 a0 = {0.f, 0.f}, a1 = {0.f, 0.f};
#pragma unroll
            for (int k2 = 0; k2 < 8; ++k2) {
                float sv0 = __shfl(s_reg, 2 * k2, 64);
                float sv1 = __shfl(s_reg, 2 * k2 + 1, 64);
                float2 w0 = h2f2(WhB[(2 * k2) * 64]);
                float2 w1 = h2f2(WhB[(2 * k2 + 1) * 64]);
                a0.x += w0.x * sv0; a0.y += w0.y * sv0;
                a1.x += w1.x * sv1; a1.y += w1.y * sv1;
            }
            part1[w * 64 + l] = make_float2(a0.x + a1.x, a0.y + a1.y);
        }
        __syncthreads();

        float a_reg;
        {
            int c = 16 * w + lr;
            const float* p1 = (const float*)part1;
            float sum = p1[c];
#pragma unroll
            for (int p = 1; p < 8; ++p) sum += p1[p * 128 + c];
            a_reg = sum + __half2float(axH[tt * 128 + c]);
        }
        {
            float2 a0 = {0.f, 0.f}, a1 = {0.f, 0.f};
#pragma unroll
            for (int k2 = 0; k2 < 8; ++k2) {
                float av0 = __shfl(a_reg, 2 * k2, 64);
                float av1 = __shfl(a_reg, 2 * k2 + 1, 64);
                float2 w0 = h2f2(DwB[(2 * k2) * 64]);
                float2 w1 = h2f2(DwB[(2 * k2 + 1) * 64]);
                a0.x += w0.x * av0; a0.y += w0.y * av0;
                a1.x += w1.x * av1; a1.y += w1.y * av1;
            }
            part2[w * 64 + l] = make_float2(a0.x + a1.x, a0.y + a1.y);
        }
        __syncthreads();

        {
            int c = 16 * w + lr;
            const float* p2 = (const float*)part2;
            float sum = p2[c];
#pragma unroll
            for (int p = 1; p < 8; ++p) sum += p2[p * 128 + c];
            float pv = fmaxf(sum + DbLw[c], 0.f);
            s_reg = stkhL[c] * pv + stkxL[c] * s_reg;
            if (l < 16) pH[tt * 128 + c] = __float2half(pv);
        }
    }
    __syncthreads();
    {
        uint2* dst = rowB + (size_t)(TT - 8) * 96;
        for (int i = tid; i < 256; i += 512)
            dst[(size_t)(i >> 5) * 96 + (i & 31)] = ((uint2*)pH)[i];
    }
}

// ===== aggmm (verified R10): o_pre = p@Aw + Ab in place =====
__global__ __launch_bounds__(256) void aggmm(
    const float* __restrict__ Aw, const float* __restrict__ Ab,
    uint2* __restrict__ axp) {
    const int bp = blockIdx.x, tg = blockIdx.y, tid = threadIdx.x;
    __shared__ uint2 AwL[12288];                 // [k*32+q] 96KB
    __shared__ __align__(16) float pT[32][384];  // 48KB
    __shared__ float AbL[128];

    for (int i = tid; i < 12288; i += 256) {
        float4 a = ((const float4*)Aw)[i];
        __half2 lo = __floats2half2_rn(a.x, a.y), hi = __floats2half2_rn(a.z, a.w);
        AwL[i] = make_uint2(*(u32*)&lo, *(u32*)&hi);
    }
    if (tid < 128) AbL[tid] = Ab[tid];

    uint2* rowBase = axp + (size_t)bp * TT * 96;
    for (int sc = 0; sc < 4; ++sc) {
        int t0 = tg * 128 + sc * 32;
        __syncthreads();
        for (int i = tid; i < 3072; i += 256) {
            int trow = i / 96, q = i % 96;
            uint2 v = rowBase[(size_t)(t0 + trow) * 96 + q];
            float2 lo = h2f2(v.x), hi = h2f2(v.y);
            pT[trow][4 * q] = lo.x;
            pT[trow][4 * q + 1] = lo.y;
            pT[trow][4 * q + 2] = hi.x;
            pT[trow][4 * q + 3] = hi.y;
        }
        __syncthreads();
#pragma unroll
        for (int it = 0; it < 4; ++it) {
            int task = tid + 256 * it;
            int trow = task >> 5, q = task & 31;
            const float* pv = &pT[trow][0];
            float4 acc = {0.f, 0.f, 0.f, 0.f};
#pragma unroll 4
            for (int k = 0; k < 384; k += 4) {
                float4 vv = *(const float4*)&pv[k];
                fma4(acc, AwL[(k + 0) * 32 + q], vv.x);
                fma4(acc, AwL[(k + 1) * 32 + q], vv.y);
                fma4(acc, AwL[(k + 2) * 32 + q], vv.z);
                fma4(acc, AwL[(k + 3) * 32 + q], vv.w);
            }
            float* dst = (float*)(rowBase + (size_t)(t0 + trow) * 96);
            float4 r;
            r.x = acc.x + AbL[4 * q];
            r.y = acc.y + AbL[4 * q + 1];
            r.z = acc.z + AbL[4 * q + 2];
            r.w = acc.w + AbL[4 * q + 3];
            *(float4*)(dst + 4 * q) = r;
        }
    }
}

// ===== gaterec4: b128 weight reads, uniform-LDS h-broadcast, 4 dot waves,
// waves 4-7 double-buffer staging. 2 barriers/step.
__global__ __launch_bounds__(512) void gaterec4(
    const float* __restrict__ Wr, const float* __restrict__ bias,
    const uint2* __restrict__ gxb, const uint2* __restrict__ axp,
    float* __restrict__ outp) {
    const int bp = blockIdx.x, tid = threadIdx.x;
    const int w = tid >> 6, l = tid & 63;

    __shared__ __align__(16) uint4 WrH4[6144];   // [k][48 octs] fp16, 96KB
    __shared__ __align__(16) uint2 gxC[2][1536]; // 2 x 16-step chunks, 24KB
    __shared__ __align__(16) float opC[2][2048]; // 16KB
    __shared__ __align__(16) float part[4][384]; // 6KB
    __shared__ __align__(16) float hS[128];
    __shared__ float biasL[384];

    // stage Wr fp32 -> fp16 LDS, uint4 i = k*48 + oct  (elem = i*8)
    for (int i = tid; i < 6144; i += 512) {
        const float4* src = (const float4*)Wr + (size_t)i * 2;
        float4 a = src[0], b = src[1];
        __half2 h0 = __floats2half2_rn(a.x, a.y);
        __half2 h1 = __floats2half2_rn(a.z, a.w);
        __half2 h2 = __floats2half2_rn(b.x, b.y);
        __half2 h3 = __floats2half2_rn(b.z, b.w);
        WrH4[i] = make_uint4(*(u32*)&h0, *(u32*)&h1, *(u32*)&h2, *(u32*)&h3);
    }
    if (tid < 384) biasL[tid] = bias[tid];
    if (tid < 128) hS[tid] = 0.f;
    float c_reg = 0.f;
    const uint2* gxRow = gxb + (size_t)bp * TT * 96;
    const float* opRow = (const float*)(axp + (size_t)bp * TT * 96);

    // prologue: stage chunk 0 into buffer 0
    for (int i = tid; i < 1536; i += 512) gxC[0][i] = gxRow[i];
    {
        int i = tid;  // 512 float4 tasks, one each
        int row = i >> 5, f4 = i & 31;
        *(float4*)&opC[0][row * 128 + 4 * f4] =
            ((const float4*)(opRow + (size_t)row * 192))[f4];
    }
    __syncthreads();

    for (int t = 0; t < TT; ++t) {
        const int tt = t & 15, buf = (t >> 4) & 1;

        if (w < 4) {
            // dot: wave w owns K-chunk [32w, 32w+32); lane l<48 owns col-oct l.
            // h via wave-uniform LDS read hS[32w+kk]: single ds_read_b32
            // broadcast per kk — no cross-lane register dependency.
            if (l < 48) {
                float a0 = 0.f, a1 = 0.f, a2 = 0.f, a3 = 0.f;
                float a4 = 0.f, a5 = 0.f, a6 = 0.f, a7 = 0.f;
                const uint4* Wp = WrH4 + (32 * w) * 48 + l;
                const float* hB = hS + 32 * w;
#pragma unroll
                for (int kk = 0; kk < 32; ++kk) {
                    uint4 wv = Wp[kk * 48];
                    float hk = hB[kk];
                    float2 c0 = h2f2(wv.x), c1 = h2f2(wv.y);
                    float2 c2 = h2f2(wv.z), c3 = h2f2(wv.w);
                    a0 += c0.x * hk; a1 += c0.y * hk;
                    a2 += c1.x * hk; a3 += c1.y * hk;
                    a4 += c2.x * hk; a5 += c2.y * hk;
                    a6 += c3.x * hk; a7 += c3.y * hk;
                }
                *(float4*)&part[w][8 * l] = make_float4(a0, a1, a2, a3);
                *(float4*)&part[w][8 * l + 4] = make_float4(a4, a5, a6, a7);
            }
        } else if (tt == 15 && t + 1 < TT) {
            // waves 4-7: stage next chunk into the other buffer; their loads
            // drain at bar1 while the dot waves are still computing.
            const int nb = buf ^ 1, tn = t + 1;
            const int i2 = tid - 256;
#pragma unroll
            for (int jj = 0; jj < 6; ++jj) {
                int f = i2 + 256 * jj;
                gxC[nb][f] = gxRow[(size_t)tn * 96 + f];
            }
#pragma unroll
            for (int jj = 0; jj < 2; ++jj) {
                int f = i2 + 256 * jj;
                int row = f >> 5, f4 = f & 31;
                *(float4*)&opC[nb][row * 128 + 4 * f4] =
                    ((const float4*)(opRow + (size_t)(tn + row) * 192))[f4];
            }
        }
        __syncthreads();

        if (tid < 128) {
            int u = tid;
            const __half* gxh = (const __half*)&gxC[buf][tt * 96];
            float gi = part[0][u] + part[1][u] + part[2][u] + part[3][u]
                     + __half2float(gxh[u]) + biasL[u];
            float gf = part[0][128 + u] + part[1][128 + u] + part[2][128 + u]
                     + part[3][128 + u]
                     + __half2float(gxh[128 + u]) + biasL[128 + u];
            float gc = part[0][256 + u] + part[1][256 + u] + part[2][256 + u]
                     + part[3][256 + u]
                     + __half2float(gxh[256 + u]) + biasL[256 + u];
            float si = sigf(gi), sf = sigf(gf), sc = sigf(gc);
            float cn = sf * c_reg + si * tanh_(sc);
            c_reg = cn;
            float hn = sigf(opC[buf][tt * 128 + u]) * tanh_(cn);
            hS[u] = hn;
            outp[((size_t)bp * TT + t) * 128 + u] = hn;
        }
        __syncthreads();
    }
}

// ===== Verified fallback (unchanged): chunk-phase kernel =====
template <bool WS>
__global__ __launch_bounds__(512, 1) void tkan(
    const float* __restrict__ xg, const float* __restrict__ Wk,
    const float* __restrict__ Wr, const float* __restrict__ bias,
    const float* __restrict__ Wx, const float* __restrict__ Wh,
    const float* __restrict__ stk, const float* __restrict__ Dw,
    const float* __restrict__ Db, const float* __restrict__ Aw,
    const float* __restrict__ Ab, const __half* __restrict__ wt,
    float* __restrict__ outp) {
    const int bp = blockIdx.x, tid = threadIdx.x;

    __shared__ float xC[4][TC][128];
    __shared__ __half gxL[TC][384];
    __shared__ __half axL[TC][384];
    __shared__ float hS[128], cS[128], tcS[128];
    __shared__ float sS[384], aS[384], pS[384], gS[384];
    __shared__ float part1[384][4], part2[192][4], part3[256][4];
    __shared__ float biasL[384], stkj[3][2][128], DbL[3][128], AbL[128];
    __shared__ float dummy[WS ? 4 : 4096];

    if (tid < 128) { hS[tid] = 0.f; cS[tid] = 0.f; AbL[tid] = Ab[tid]; }
    if (tid >= 128 && tid < 512) {
        int q = tid - 128;
        sS[q] = 0.f;
        biasL[q] = bias[q];
    }
    {
        int j = tid >> 7, o = tid & 127;
        if (j < 3) {
            int nj = (3 * bp + j) >> 6;
            stkj[j][0][o] = stk[nj * 256 + o];
            stkj[j][1][o] = stk[nj * 256 + 128 + o];
            DbL[j][o] = Db[nj * 128 + o];
        }
    }
    if (bias[0] > 1e30f) { dummy[tid & 3] = 1.f; }
    __syncthreads();

    const float4* Wk4 = (const float4*)Wk;
    const float4* Wx4 = (const float4*)Wx;
    const void* wWr = WS ? (const void*)(wt)          : (const void*)Wr;
    const void* wWh = WS ? (const void*)(wt + 49152)  : (const void*)Wh;
    const void* wDw = WS ? (const void*)(wt + 98304)  : (const void*)Dw;
    const void* wAw = WS ? (const void*)(wt + 147456) : (const void*)Aw;

    for (int t = 0; t < TT; ++t) {
        int tt = t & (TC - 1);
        if (tt == 0) {
            for (int f = tid; f < 4096; f += 512) {
                int v_ = f >> 10, ti = (f >> 5) & 31, kq = f & 31;
                int row = (v_ == 0) ? bp : ((3 * bp + (v_ - 1)) & 63);
                float4 w = ((const float4*)(xg + ((size_t)row * TT + t + ti) * 128))[kq];
                float* d = &xC[v_][ti][kq * 4];
                d[0] = w.x; d[1] = w.y; d[2] = w.z; d[3] = w.w;
            }
            __syncthreads();
            for (int ct = tid; ct < TC * 192; ct += 512) {
                int ti = ct / 192, r = ct % 192;
                float4 acc = {0.f, 0.f, 0.f, 0.f};
                if (r < 96) {
                    const float* v = xC[0][ti];
#pragma unroll 8
                    for (int k = 0; k < 128; ++k) {
                        float4 w = Wk4[k * 96 + r];
                        float xv = v[k];
                        acc.x += w.x * xv; acc.y += w.y * xv;
                        acc.z += w.z * xv; acc.w += w.w * xv;
                    }
                    int qout = r;
                    ((__half2*)&gxL[ti][0])[2 * qout] = __floats2half2_rn(acc.x, acc.y);
                    ((__half2*)&gxL[ti][0])[2 * qout + 1] = __floats2half2_rn(acc.z, acc.w);
                } else {
                    int jq = r - 96, j = jq >> 5, qi = jq & 31;
                    int nj = (3 * bp + j) >> 6;
                    const float* v = xC[1 + j][ti];
#pragma unroll 8
                    for (int k = 0; k < 128; ++k) {
                        float4 w = Wx4[nj * 4096 + k * 32 + qi];
                        float xv = v[k];
                        acc.x += w.x * xv; acc.y += w.y * xv;
                        acc.z += w.z * xv; acc.w += w.w * xv;
                    }
                    int cq = j * 32 + qi;
                    ((__half2*)&axL[ti][0])[2 * cq] = __floats2half2_rn(acc.x, acc.y);
                    ((__half2*)&axL[ti][0])[2 * cq + 1] = __floats2half2_rn(acc.z, acc.w);
                }
            }
            __syncthreads();
        }

        if (tid < 384) {
            float4 acc = {0.f, 0.f, 0.f, 0.f};
            if (tid < 192) {
                int q = tid % 96, ks = tid / 96;
                dotq<WS>(wWr, q, 96, hS, ks * 64, 64, acc);
            } else {
                int t2 = tid - 192;
                int jq = t2 % 96, ks = t2 / 96;
                int j = jq >> 5, qi = jq & 31;
                int nj = (3 * bp + j) >> 6;
                dotq<WS>(wWh, nj * 4096 + qi, 32, sS + j * 128, ks * 64, 64, acc);
            }
            *(float4*)&part1[tid][0] = acc;
        }
        __syncthreads();

        if (tid < 192) {
            if (tid < 96) {
                int q = tid;
                float4 a0 = *(float4*)&part1[q][0];
                float4 a1 = *(float4*)&part1[q + 96][0];
                float2 g0 = h2f2(((const u32*)&gxL[tt][0])[2 * q]);
                float2 g1 = h2f2(((const u32*)&gxL[tt][0])[2 * q + 1]);
                float4 r;
                r.x = a0.x + a1.x + g0.x + biasL[4 * q];
                r.y = a0.y + a1.y + g0.y + biasL[4 * q + 1];
                r.z = a0.z + a1.z + g1.x + biasL[4 * q + 2];
                r.w = a0.w + a1.w + g1.y + biasL[4 * q + 3];
                *(float4*)&gS[4 * q] = r;
            } else {
                int cq = tid - 96;
                float4 a0 = *(float4*)&part1[192 + cq][0];
                float4 a1 = *(float4*)&part1[288 + cq][0];
                float2 g0 = h2f2(((const u32*)&axL[tt][0])[2 * cq]);
                float2 g1 = h2f2(((const u32*)&axL[tt][0])[2 * cq + 1]);
                float4 r;
                r.x = a0.x + a1.x + g0.x;
                r.y = a0.y + a1.y + g0.y;
                r.z = a0.z + a1.z + g1.x;
                r.w = a0.w + a1.w + g1.y;
                *(float4*)&aS[4 * cq] = r;
            }
        }
        __syncthreads();

        if (tid < 192) {
            int q = tid % 96, ks = tid / 96;
            int j = q >> 5, qi = q & 31;
            int nj = (3 * bp + j) >> 6;
            float4 acc = {0.f, 0.f, 0.f, 0.f};
            dotq<WS>(wDw, nj * 4096 + qi, 32, aS + j * 128, ks * 64, 64, acc);
            *(float4*)&part2[tid][0] = acc;
        } else if (tid >= 384) {
            int u = tid - 384;
            float gi = sigf(gS[u]);
            float gf = sigf(gS[128 + u]);
            float gc = sigf(gS[256 + u]);
            float cn = gf * cS[u] + gi * tanh_(gc);
            cS[u] = cn;
            tcS[u] = tanh_(cn);
        }
        __syncthreads();

        if (tid < 96) {
            int j = tid >> 5, o = (tid & 31) * 4;
            float4 a0 = *(float4*)&part2[tid][0];
            float4 a1 = *(float4*)&part2[tid + 96][0];
            float4 r;
            r.x = fmaxf(a0.x + a1.x + DbL[j][o], 0.f);
            r.y = fmaxf(a0.y + a1.y + DbL[j][o + 1], 0.f);
            r.z = fmaxf(a0.z + a1.z + DbL[j][o + 2], 0.f);
            r.w = fmaxf(a0.w + a1.w + DbL[j][o + 3], 0.f);
            *(float4*)&pS[4 * tid] = r;
        }
        __syncthreads();

        if (tid < 256) {
            int q = tid & 31, ks = tid >> 5;
            float4 acc = {0.f, 0.f, 0.f, 0.f};
            dotq<WS>(wAw, q, 32, pS, ks * 48, 48, acc);
            *(float4*)&part3[tid][0] = acc;
        } else if (tid < 384) {
            int e = tid - 256;
#pragma unroll
            for (int j = 0; j < 3; ++j) {
                int q = j * 128 + e;
                sS[q] = stkj[j][0][e] * pS[q] + stkj[j][1][e] * sS[q];
            }
        }
        __syncthreads();

        if (tid < 128) {
            int u = tid;
            float y = AbL[u];
#pragma unroll
            for (int ks = 0; ks < 8; ++ks) y += part3[ks * 32 + (u >> 2)][u & 3];
            float hn = sigf(y) * tcS[u];
            hS[u] = hn;
            outp[((size_t)bp * TT + t) * 128 + u] = hn;
        }
        __syncthreads();
    }
}

extern "C" void kernel_launch(void* const* d_in, const int* in_sizes, int n_in,
                              void* d_out, int out_size, void* d_ws, size_t ws_size,
                              hipStream_t stream) {
    const float* x    = (const float*)d_in[0];
    const float* Wk   = (const float*)d_in[1];
    const float* Wr   = (const float*)d_in[2];
    const float* bias = (const float*)d_in[3];
    const float* Wx   = (const float*)d_in[4];
    const float* Wh   = (const float*)d_in[5];
    const float* stk  = (const float*)d_in[6];
    const float* Dw   = (const float*)d_in[7];
    const float* Db   = (const float*)d_in[8];
    const float* Aw   = (const float*)d_in[9];
    const float* Ab   = (const float*)d_in[10];
    float* outp = (float*)d_out;

    const size_t needNew = (size_t)2 * BB * TT * 384 * sizeof(__half);  // 201,326,592
    const size_t needW   = 196608 * sizeof(__half);                     // fp16 weights
    if (ws_size >= needNew) {
        uint2* gxb = (uint2*)d_ws;
        uint2* axb = gxb + (size_t)BB * TT * 96;
        gax_pre2<<<dim3(BB, 64), dim3(384), 0, stream>>>(x, Wk, Wx, gxb, axb);
        subrec3<<<dim3(BB, 3), dim3(512), 0, stream>>>(Wh, Dw, stk, Db, axb);
        aggmm<<<dim3(BB, 16), dim3(256), 0, stream>>>(Aw, Ab, axb);
        gaterec4<<<dim3(BB), dim3(512), 0, stream>>>(Wr, bias, gxb, axb, outp);
    } else if (ws_size >= needW) {
        __half* wt = (__half*)d_ws;
        convert_w<<<dim3(384), dim3(512), 0, stream>>>(Wr, Wh, Dw, Aw, wt);
        tkan<true><<<dim3(BB), dim3(512), 0, stream>>>(
            x, Wk, Wr, bias, Wx, Wh, stk, Dw, Db, Aw, Ab, wt, outp);
    } else {
        tkan<false><<<dim3(BB), dim3(512), 0, stream>>>(
            x, Wk, Wr, bias, Wx, Wh, stk, Dw, Db, Aw, Ab, (const __half*)nullptr,
            outp);
    }
}

// Round 13
// 5347.149 us; speedup vs baseline: 2.6400x; 1.2666x over previous
//
#include <hip/hip_runtime.h>
#include <hip/hip_fp16.h>

// TKANCell B=64,T=2048,D=128,U=128,NS=3 — fp32 in/out.
// 64 independent chains (tf.reshape routes sub-row r=3b'+j to batch b'=r/3).
// R18: R15 measured 6.77ms; subrec3 now top at 2.90ms, LDS-issue bound
// (shfl = ds_bpermute; 650 LDS wave-ops/step). subrec5: per-wave K-slice 16
// -> only 32 VGPRs of weights per lane (whr[16]+dwr[16] u32, compile-time
// indexed — 3.5x below the R7/R8 spill threshold), dots = 4 uniform-float4
// broadcasts + register MACs + 1 float2 partial write; reduces are WAVE-
// LOCAL (wave w owns cols [16w,16w+16); stk/Db/s in owner-lane registers)
// so still 2 barriers/step. gaterec4: h-broadcast batched as uniform float4
// (32 b32 -> 8 b128 per wave). aggmm/gax_pre2/fallbacks unchanged.

#define TT 2048
#define BB 64
#define TC 32

typedef unsigned int u32;

__device__ __forceinline__ float sigf(float x) { return 1.f / (1.f + __expf(-x)); }
__device__ __forceinline__ float tanh_(float x) { return 2.f / (1.f + __expf(-2.f * x)) - 1.f; }
__device__ __forceinline__ float2 h2f2(u32 u) {
    __half2 h = *(__half2*)&u;
    return __half22float2(h);
}

__device__ __forceinline__ void fma4(float4& acc, uint2 w, float xv) {
    float2 lo = h2f2(w.x), hi = h2f2(w.y);
    acc.x += lo.x * xv; acc.y += lo.y * xv;
    acc.z += hi.x * xv; acc.w += hi.y * xv;
}

// legacy dot for fallback kernel
template <bool WS>
__device__ __forceinline__ void dotq(const void* W, int idxBase, int stride,
                                     const float* __restrict__ v, int k0, int kn,
                                     float4& acc) {
    if (WS) {
        const uint2* Wp = (const uint2*)W;
#pragma unroll 8
        for (int k = k0; k < k0 + kn; ++k) {
            uint2 w = Wp[idxBase + k * stride];
            float2 lo = h2f2(w.x), hi = h2f2(w.y);
            float xv = v[k];
            acc.x += lo.x * xv; acc.y += lo.y * xv;
            acc.z += hi.x * xv; acc.w += hi.y * xv;
        }
    } else {
        const float4* Wp = (const float4*)W;
#pragma unroll 8
        for (int k = k0; k < k0 + kn; ++k) {
            float4 w = Wp[idxBase + k * stride];
            float xv = v[k];
            acc.x += w.x * xv; acc.y += w.y * xv;
            acc.z += w.z * xv; acc.w += w.w * xv;
        }
    }
}

// fp16 copy of Wr|Wh|Dw|Aw (fallback tier only).
__global__ __launch_bounds__(512) void convert_w(
    const float* __restrict__ Wr, const float* __restrict__ Wh,
    const float* __restrict__ Dw, const float* __restrict__ Aw,
    __half* __restrict__ dst) {
    int g = blockIdx.x * 512 + threadIdx.x;  // 0..196607
    int seg = g / 49152, idx = g % 49152;
    const float* src = (seg == 0) ? Wr : (seg == 1) ? Wh : (seg == 2) ? Dw : Aw;
    dst[g] = __float2half(src[idx]);
}

// ===== pre-pass: gx[bp][t][96quads] = x@Wk ; ax[bp][t][96quads] = x@Wx.
__global__ __launch_bounds__(384, 3) void gax_pre2(
    const float* __restrict__ xg, const float* __restrict__ Wk,
    const float* __restrict__ Wx, uint2* __restrict__ gxb,
    uint2* __restrict__ axb) {
    const int bp = blockIdx.x, tc = blockIdx.y, tid = threadIdx.x;
    const int t0 = tc * 32;
    __shared__ __align__(16) float xCt[4][128][32];  // 64KB, [v][k][ti]

    for (int f = tid; f < 4096; f += 384) {
        int v_ = f >> 10, ti = (f >> 5) & 31, kq = f & 31;
        int row = (v_ == 0) ? bp : ((3 * bp + (v_ - 1)) & 63);
        float4 w = ((const float4*)(xg + ((size_t)row * TT + t0 + ti) * 128))[kq];
        xCt[v_][4 * kq + 0][ti] = w.x;
        xCt[v_][4 * kq + 1][ti] = w.y;
        xCt[v_][4 * kq + 2][ti] = w.z;
        xCt[v_][4 * kq + 3][ti] = w.w;
    }
    __syncthreads();

    const float4* Wk4 = (const float4*)Wk;
    const float4* Wx4 = (const float4*)Wx;

    for (int task = tid; task < 768; task += 384) {
        int grp = task / 192, r = task % 192;
        int ti0 = grp * 8;
        const float4* Wp;
        int base, stride, v;
        if (r < 96) {
            Wp = Wk4; base = r; stride = 96; v = 0;
        } else {
            int jq = r - 96, j = jq >> 5, qi = jq & 31;
            int nj = (3 * bp + j) >> 6;
            Wp = Wx4; base = nj * 4096 + qi; stride = 32; v = 1 + j;
        }
        float4 acc[8];
#pragma unroll
        for (int i = 0; i < 8; ++i) acc[i] = make_float4(0.f, 0.f, 0.f, 0.f);
#pragma unroll 4
        for (int k = 0; k < 128; ++k) {
            float4 w = Wp[base + k * stride];
            float4 xa = *(const float4*)&xCt[v][k][ti0];
            float4 xb = *(const float4*)&xCt[v][k][ti0 + 4];
#pragma unroll
            for (int i = 0; i < 4; ++i) {
                float xv = (&xa.x)[i];
                acc[i].x += w.x * xv; acc[i].y += w.y * xv;
                acc[i].z += w.z * xv; acc[i].w += w.w * xv;
            }
#pragma unroll
            for (int i = 0; i < 4; ++i) {
                float xv = (&xb.x)[i];
                acc[4 + i].x += w.x * xv; acc[4 + i].y += w.y * xv;
                acc[4 + i].z += w.z * xv; acc[4 + i].w += w.w * xv;
            }
        }
#pragma unroll
        for (int i = 0; i < 8; ++i) {
            size_t rowo = ((size_t)bp * TT + (size_t)(t0 + ti0 + i)) * 96;
            __half2 lo = __floats2half2_rn(acc[i].x, acc[i].y);
            __half2 hi = __floats2half2_rn(acc[i].z, acc[i].w);
            uint2 pk = make_uint2(*(u32*)&lo, *(u32*)&hi);
            if (r < 96) gxb[rowo + r] = pk;
            else        axb[rowo + (r - 96)] = pk;
        }
    }
}

// ===== subrec5: s-recurrence, 192 blocks; weights in REGISTERS (32 VGPR),
// wave-local reduces (wave w owns cols [16w,16w+16)), 2 barriers/step.
__global__ __launch_bounds__(512) void subrec5(
    const float* __restrict__ Wh, const float* __restrict__ Dw,
    const float* __restrict__ stk, const float* __restrict__ Db,
    uint2* __restrict__ axp) {
    const int bp = blockIdx.x, j = blockIdx.y, tid = threadIdx.x;
    const int w = tid >> 6, l = tid & 63;
    const int nj = (3 * bp + j) >> 6;

    __shared__ __align__(16) float sS[128], aS[128];
    __shared__ __align__(16) float part1[1024], part2[1024];  // [w][128]
    __shared__ __align__(16) __half axH[1024], pH[1024];      // [8][128]

    // weight regs: k in [16w, 16w+16), cols (2l, 2l+1). Compile-time indexed.
    u32 whr[16], dwr[16];
    {
        const float2* Wh2 = (const float2*)Wh + (size_t)nj * 8192;
        const float2* Dw2 = (const float2*)Dw + (size_t)nj * 8192;
#pragma unroll
        for (int i = 0; i < 16; ++i) {
            float2 a = Wh2[(16 * w + i) * 64 + l];
            float2 b = Dw2[(16 * w + i) * 64 + l];
            __half2 ah = __floats2half2_rn(a.x, a.y);
            __half2 bh = __floats2half2_rn(b.x, b.y);
            whr[i] = *(u32*)&ah;
            dwr[i] = *(u32*)&bh;
        }
    }
    // owner-lane (l<16) per-col constants: c_own = 16w + (l&15)
    const int c_own = 16 * w + (l & 15);
    const float stk_h = stk[nj * 256 + c_own];
    const float stk_x = stk[nj * 256 + 128 + c_own];
    const float db_c = Db[nj * 128 + c_own];
    float s_own = 0.f;
    if (tid < 128) sS[tid] = 0.f;
    uint2* rowB = axp + (size_t)bp * TT * 96 + 32 * j;
    __syncthreads();

    for (int t = 0; t < TT; ++t) {
        const int tt = t & 7;
        if (tt == 0) {
            __syncthreads();  // all reduce2 pH writes + part2 readers done
            if (t) {          // flush p chunk [t-8, t)
                uint2* dst = rowB + (size_t)(t - 8) * 96;
                for (int i = tid; i < 256; i += 512)
                    dst[(size_t)(i >> 5) * 96 + (i & 31)] = ((uint2*)pH)[i];
            }
            const uint2* src = rowB + (size_t)t * 96;
            for (int i = tid; i < 256; i += 512)
                ((uint2*)axH)[i] = src[(size_t)(i >> 5) * 96 + (i & 31)];
            __syncthreads();
        }

        // ph1: acc(2 cols) = sum_{i<16} s[16w+i] * whr[i]; s via uniform f4.
        {
            float2 acc = {0.f, 0.f};
#pragma unroll
            for (int ii = 0; ii < 4; ++ii) {
                float4 sv = *(const float4*)&sS[16 * w + 4 * ii];
                float2 w0 = h2f2(whr[4 * ii + 0]);
                float2 w1 = h2f2(whr[4 * ii + 1]);
                float2 w2 = h2f2(whr[4 * ii + 2]);
                float2 w3 = h2f2(whr[4 * ii + 3]);
                acc.x += w0.x * sv.x; acc.y += w0.y * sv.x;
                acc.x += w1.x * sv.y; acc.y += w1.y * sv.y;
                acc.x += w2.x * sv.z; acc.y += w2.y * sv.z;
                acc.x += w3.x * sv.w; acc.y += w3.y * sv.w;
            }
            *(float2*)&part1[w * 128 + 2 * l] = acc;
        }
        __syncthreads();  // BAR A: part1 complete

        // reduce1 (wave-local): owner lanes sum 8 partials + ax -> aS slice.
        if (l < 16) {
            float sum = part1[c_own];
#pragma unroll
            for (int p = 1; p < 8; ++p) sum += part1[p * 128 + c_own];
            sum += __half2float(axH[tt * 128 + c_own]);
            aS[c_own] = sum;
        }
        // no barrier: aS[16w..16w+16) written and read only by wave w.

        // ph2: p-partial = sum agg * dwr
        {
            float2 acc = {0.f, 0.f};
#pragma unroll
            for (int ii = 0; ii < 4; ++ii) {
                float4 av = *(const float4*)&aS[16 * w + 4 * ii];
                float2 w0 = h2f2(dwr[4 * ii + 0]);
                float2 w1 = h2f2(dwr[4 * ii + 1]);
                float2 w2 = h2f2(dwr[4 * ii + 2]);
                float2 w3 = h2f2(dwr[4 * ii + 3]);
                acc.x += w0.x * av.x; acc.y += w0.y * av.x;
                acc.x += w1.x * av.y; acc.y += w1.y * av.y;
                acc.x += w2.x * av.z; acc.y += w2.y * av.z;
                acc.x += w3.x * av.w; acc.y += w3.y * av.w;
            }
            *(float2*)&part2[w * 128 + 2 * l] = acc;
        }
        __syncthreads();  // BAR B: part2 complete

        // reduce2 (wave-local): p = relu(+Db); s-update in registers; pH.
        if (l < 16) {
            float sum = part2[c_own];
#pragma unroll
            for (int p = 1; p < 8; ++p) sum += part2[p * 128 + c_own];
            float pv = fmaxf(sum + db_c, 0.f);
            s_own = stk_h * pv + stk_x * s_own;
            sS[c_own] = s_own;
            pH[tt * 128 + c_own] = __float2half(pv);
        }
        // no barrier: sS slice wave-local; next write to part1 is after this
        // wave's own reduce2; cross-wave part hazards covered by BAR A/B.
    }
    __syncthreads();
    {
        uint2* dst = rowB + (size_t)(TT - 8) * 96;
        for (int i = tid; i < 256; i += 512)
            dst[(size_t)(i >> 5) * 96 + (i & 31)] = ((uint2*)pH)[i];
    }
}

// ===== aggmm (verified R10): o_pre = p@Aw + Ab in place =====
__global__ __launch_bounds__(256) void aggmm(
    const float* __restrict__ Aw, const float* __restrict__ Ab,
    uint2* __restrict__ axp) {
    const int bp = blockIdx.x, tg = blockIdx.y, tid = threadIdx.x;
    __shared__ uint2 AwL[12288];                 // [k*32+q] 96KB
    __shared__ __align__(16) float pT[32][384];  // 48KB
    __shared__ float AbL[128];

    for (int i = tid; i < 12288; i += 256) {
        float4 a = ((const float4*)Aw)[i];
        __half2 lo = __floats2half2_rn(a.x, a.y), hi = __floats2half2_rn(a.z, a.w);
        AwL[i] = make_uint2(*(u32*)&lo, *(u32*)&hi);
    }
    if (tid < 128) AbL[tid] = Ab[tid];

    uint2* rowBase = axp + (size_t)bp * TT * 96;
    for (int sc = 0; sc < 4; ++sc) {
        int t0 = tg * 128 + sc * 32;
        __syncthreads();
        for (int i = tid; i < 3072; i += 256) {
            int trow = i / 96, q = i % 96;
            uint2 v = rowBase[(size_t)(t0 + trow) * 96 + q];
            float2 lo = h2f2(v.x), hi = h2f2(v.y);
            pT[trow][4 * q] = lo.x;
            pT[trow][4 * q + 1] = lo.y;
            pT[trow][4 * q + 2] = hi.x;
            pT[trow][4 * q + 3] = hi.y;
        }
        __syncthreads();
#pragma unroll
        for (int it = 0; it < 4; ++it) {
            int task = tid + 256 * it;
            int trow = task >> 5, q = task & 31;
            const float* pv = &pT[trow][0];
            float4 acc = {0.f, 0.f, 0.f, 0.f};
#pragma unroll 4
            for (int k = 0; k < 384; k += 4) {
                float4 vv = *(const float4*)&pv[k];
                fma4(acc, AwL[(k + 0) * 32 + q], vv.x);
                fma4(acc, AwL[(k + 1) * 32 + q], vv.y);
                fma4(acc, AwL[(k + 2) * 32 + q], vv.z);
                fma4(acc, AwL[(k + 3) * 32 + q], vv.w);
            }
            float* dst = (float*)(rowBase + (size_t)(t0 + trow) * 96);
            float4 r;
            r.x = acc.x + AbL[4 * q];
            r.y = acc.y + AbL[4 * q + 1];
            r.z = acc.z + AbL[4 * q + 2];
            r.w = acc.w + AbL[4 * q + 3];
            *(float4*)(dst + 4 * q) = r;
        }
    }
}

// ===== gaterec4 (verified R15) + batched float4 h-broadcast.
__global__ __launch_bounds__(512) void gaterec4(
    const float* __restrict__ Wr, const float* __restrict__ bias,
    const uint2* __restrict__ gxb, const uint2* __restrict__ axp,
    float* __restrict__ outp) {
    const int bp = blockIdx.x, tid = threadIdx.x;
    const int w = tid >> 6, l = tid & 63;

    __shared__ __align__(16) uint4 WrH4[6144];   // [k][48 octs] fp16, 96KB
    __shared__ __align__(16) uint2 gxC[2][1536]; // 2 x 16-step chunks, 24KB
    __shared__ __align__(16) float opC[2][2048]; // 16KB
    __shared__ __align__(16) float part[4][384]; // 6KB
    __shared__ __align__(16) float hS[128];
    __shared__ float biasL[384];

    // stage Wr fp32 -> fp16 LDS, uint4 i = k*48 + oct  (elem = i*8)
    for (int i = tid; i < 6144; i += 512) {
        const float4* src = (const float4*)Wr + (size_t)i * 2;
        float4 a = src[0], b = src[1];
        __half2 h0 = __floats2half2_rn(a.x, a.y);
        __half2 h1 = __floats2half2_rn(a.z, a.w);
        __half2 h2 = __floats2half2_rn(b.x, b.y);
        __half2 h3 = __floats2half2_rn(b.z, b.w);
        WrH4[i] = make_uint4(*(u32*)&h0, *(u32*)&h1, *(u32*)&h2, *(u32*)&h3);
    }
    if (tid < 384) biasL[tid] = bias[tid];
    if (tid < 128) hS[tid] = 0.f;
    float c_reg = 0.f;
    const uint2* gxRow = gxb + (size_t)bp * TT * 96;
    const float* opRow = (const float*)(axp + (size_t)bp * TT * 96);

    // prologue: stage chunk 0 into buffer 0
    for (int i = tid; i < 1536; i += 512) gxC[0][i] = gxRow[i];
    {
        int i = tid;  // 512 float4 tasks, one each
        int row = i >> 5, f4 = i & 31;
        *(float4*)&opC[0][row * 128 + 4 * f4] =
            ((const float4*)(opRow + (size_t)row * 192))[f4];
    }
    __syncthreads();

    for (int t = 0; t < TT; ++t) {
        const int tt = t & 15, buf = (t >> 4) & 1;

        if (w < 4) {
            // dot: wave w owns K-chunk [32w, 32w+32); lane l<48 owns col-oct l.
            // h via uniform float4 LDS reads (8 b128 ops vs 32 b32).
            if (l < 48) {
                float a0 = 0.f, a1 = 0.f, a2 = 0.f, a3 = 0.f;
                float a4 = 0.f, a5 = 0.f, a6 = 0.f, a7 = 0.f;
                const uint4* Wp = WrH4 + (32 * w) * 48 + l;
                const float4* hB4 = (const float4*)(hS + 32 * w);
#pragma unroll
                for (int kk4 = 0; kk4 < 8; ++kk4) {
                    float4 h4 = hB4[kk4];
#pragma unroll
                    for (int q = 0; q < 4; ++q) {
                        uint4 wv = Wp[(4 * kk4 + q) * 48];
                        float hk = (&h4.x)[q];
                        float2 c0 = h2f2(wv.x), c1 = h2f2(wv.y);
                        float2 c2 = h2f2(wv.z), c3 = h2f2(wv.w);
                        a0 += c0.x * hk; a1 += c0.y * hk;
                        a2 += c1.x * hk; a3 += c1.y * hk;
                        a4 += c2.x * hk; a5 += c2.y * hk;
                        a6 += c3.x * hk; a7 += c3.y * hk;
                    }
                }
                *(float4*)&part[w][8 * l] = make_float4(a0, a1, a2, a3);
                *(float4*)&part[w][8 * l + 4] = make_float4(a4, a5, a6, a7);
            }
        } else if (tt == 15 && t + 1 < TT) {
            // waves 4-7: stage next chunk into the other buffer; their loads
            // drain at bar1 while the dot waves are still computing.
            const int nb = buf ^ 1, tn = t + 1;
            const int i2 = tid - 256;
#pragma unroll
            for (int jj = 0; jj < 6; ++jj) {
                int f = i2 + 256 * jj;
                gxC[nb][f] = gxRow[(size_t)tn * 96 + f];
            }
#pragma unroll
            for (int jj = 0; jj < 2; ++jj) {
                int f = i2 + 256 * jj;
                int row = f >> 5, f4 = f & 31;
                *(float4*)&opC[nb][row * 128 + 4 * f4] =
                    ((const float4*)(opRow + (size_t)(tn + row) * 192))[f4];
            }
        }
        __syncthreads();

        if (tid < 128) {
            int u = tid;
            const __half* gxh = (const __half*)&gxC[buf][tt * 96];
            float gi = part[0][u] + part[1][u] + part[2][u] + part[3][u]
                     + __half2float(gxh[u]) + biasL[u];
            float gf = part[0][128 + u] + part[1][128 + u] + part[2][128 + u]
                     + part[3][128 + u]
                     + __half2float(gxh[128 + u]) + biasL[128 + u];
            float gc = part[0][256 + u] + part[1][256 + u] + part[2][256 + u]
                     + part[3][256 + u]
                     + __half2float(gxh[256 + u]) + biasL[256 + u];
            float si = sigf(gi), sf = sigf(gf), sc = sigf(gc);
            float cn = sf * c_reg + si * tanh_(sc);
            c_reg = cn;
            float hn = sigf(opC[buf][tt * 128 + u]) * tanh_(cn);
            hS[u] = hn;
            outp[((size_t)bp * TT + t) * 128 + u] = hn;
        }
        __syncthreads();
    }
}

// ===== Verified fallback (unchanged): chunk-phase kernel =====
template <bool WS>
__global__ __launch_bounds__(512, 1) void tkan(
    const float* __restrict__ xg, const float* __restrict__ Wk,
    const float* __restrict__ Wr, const float* __restrict__ bias,
    const float* __restrict__ Wx, const float* __restrict__ Wh,
    const float* __restrict__ stk, const float* __restrict__ Dw,
    const float* __restrict__ Db, const float* __restrict__ Aw,
    const float* __restrict__ Ab, const __half* __restrict__ wt,
    float* __restrict__ outp) {
    const int bp = blockIdx.x, tid = threadIdx.x;

    __shared__ float xC[4][TC][128];
    __shared__ __half gxL[TC][384];
    __shared__ __half axL[TC][384];
    __shared__ float hS[128], cS[128], tcS[128];
    __shared__ float sS[384], aS[384], pS[384], gS[384];
    __shared__ float part1[384][4], part2[192][4], part3[256][4];
    __shared__ float biasL[384], stkj[3][2][128], DbL[3][128], AbL[128];
    __shared__ float dummy[WS ? 4 : 4096];

    if (tid < 128) { hS[tid] = 0.f; cS[tid] = 0.f; AbL[tid] = Ab[tid]; }
    if (tid >= 128 && tid < 512) {
        int q = tid - 128;
        sS[q] = 0.f;
        biasL[q] = bias[q];
    }
    {
        int j = tid >> 7, o = tid & 127;
        if (j < 3) {
            int nj = (3 * bp + j) >> 6;
            stkj[j][0][o] = stk[nj * 256 + o];
            stkj[j][1][o] = stk[nj * 256 + 128 + o];
            DbL[j][o] = Db[nj * 128 + o];
        }
    }
    if (bias[0] > 1e30f) { dummy[tid & 3] = 1.f; }
    __syncthreads();

    const float4* Wk4 = (const float4*)Wk;
    const float4* Wx4 = (const float4*)Wx;
    const void* wWr = WS ? (const void*)(wt)          : (const void*)Wr;
    const void* wWh = WS ? (const void*)(wt + 49152)  : (const void*)Wh;
    const void* wDw = WS ? (const void*)(wt + 98304)  : (const void*)Dw;
    const void* wAw = WS ? (const void*)(wt + 147456) : (const void*)Aw;

    for (int t = 0; t < TT; ++t) {
        int tt = t & (TC - 1);
        if (tt == 0) {
            for (int f = tid; f < 4096; f += 512) {
                int v_ = f >> 10, ti = (f >> 5) & 31, kq = f & 31;
                int row = (v_ == 0) ? bp : ((3 * bp + (v_ - 1)) & 63);
                float4 w = ((const float4*)(xg + ((size_t)row * TT + t + ti) * 128))[kq];
                float* d = &xC[v_][ti][kq * 4];
                d[0] = w.x; d[1] = w.y; d[2] = w.z; d[3] = w.w;
            }
            __syncthreads();
            for (int ct = tid; ct < TC * 192; ct += 512) {
                int ti = ct / 192, r = ct % 192;
                float4 acc = {0.f, 0.f, 0.f, 0.f};
                if (r < 96) {
                    const float* v = xC[0][ti];
#pragma unroll 8
                    for (int k = 0; k < 128; ++k) {
                        float4 w = Wk4[k * 96 + r];
                        float xv = v[k];
                        acc.x += w.x * xv; acc.y += w.y * xv;
                        acc.z += w.z * xv; acc.w += w.w * xv;
                    }
                    int qout = r;
                    ((__half2*)&gxL[ti][0])[2 * qout] = __floats2half2_rn(acc.x, acc.y);
                    ((__half2*)&gxL[ti][0])[2 * qout + 1] = __floats2half2_rn(acc.z, acc.w);
                } else {
                    int jq = r - 96, j = jq >> 5, qi = jq & 31;
                    int nj = (3 * bp + j) >> 6;
                    const float* v = xC[1 + j][ti];
#pragma unroll 8
                    for (int k = 0; k < 128; ++k) {
                        float4 w = Wx4[nj * 4096 + k * 32 + qi];
                        float xv = v[k];
                        acc.x += w.x * xv; acc.y += w.y * xv;
                        acc.z += w.z * xv; acc.w += w.w * xv;
                    }
                    int cq = j * 32 + qi;
                    ((__half2*)&axL[ti][0])[2 * cq] = __floats2half2_rn(acc.x, acc.y);
                    ((__half2*)&axL[ti][0])[2 * cq + 1] = __floats2half2_rn(acc.z, acc.w);
                }
            }
            __syncthreads();
        }

        if (tid < 384) {
            float4 acc = {0.f, 0.f, 0.f, 0.f};
            if (tid < 192) {
                int q = tid % 96, ks = tid / 96;
                dotq<WS>(wWr, q, 96, hS, ks * 64, 64, acc);
            } else {
                int t2 = tid - 192;
                int jq = t2 % 96, ks = t2 / 96;
                int j = jq >> 5, qi = jq & 31;
                int nj = (3 * bp + j) >> 6;
                dotq<WS>(wWh, nj * 4096 + qi, 32, sS + j * 128, ks * 64, 64, acc);
            }
            *(float4*)&part1[tid][0] = acc;
        }
        __syncthreads();

        if (tid < 192) {
            if (tid < 96) {
                int q = tid;
                float4 a0 = *(float4*)&part1[q][0];
                float4 a1 = *(float4*)&part1[q + 96][0];
                float2 g0 = h2f2(((const u32*)&gxL[tt][0])[2 * q]);
                float2 g1 = h2f2(((const u32*)&gxL[tt][0])[2 * q + 1]);
                float4 r;
                r.x = a0.x + a1.x + g0.x + biasL[4 * q];
                r.y = a0.y + a1.y + g0.y + biasL[4 * q + 1];
                r.z = a0.z + a1.z + g1.x + biasL[4 * q + 2];
                r.w = a0.w + a1.w + g1.y + biasL[4 * q + 3];
                *(float4*)&gS[4 * q] = r;
            } else {
                int cq = tid - 96;
                float4 a0 = *(float4*)&part1[192 + cq][0];
                float4 a1 = *(float4*)&part1[288 + cq][0];
                float2 g0 = h2f2(((const u32*)&axL[tt][0])[2 * cq]);
                float2 g1 = h2f2(((const u32*)&axL[tt][0])[2 * cq + 1]);
                float4 r;
                r.x = a0.x + a1.x + g0.x;
                r.y = a0.y + a1.y + g0.y;
                r.z = a0.z + a1.z + g1.x;
                r.w = a0.w + a1.w + g1.y;
                *(float4*)&aS[4 * cq] = r;
            }
        }
        __syncthreads();

        if (tid < 192) {
            int q = tid % 96, ks = tid / 96;
            int j = q >> 5, qi = q & 31;
            int nj = (3 * bp + j) >> 6;
            float4 acc = {0.f, 0.f, 0.f, 0.f};
            dotq<WS>(wDw, nj * 4096 + qi, 32, aS + j * 128, ks * 64, 64, acc);
            *(float4*)&part2[tid][0] = acc;
        } else if (tid >= 384) {
            int u = tid - 384;
            float gi = sigf(gS[u]);
            float gf = sigf(gS[128 + u]);
            float gc = sigf(gS[256 + u]);
            float cn = gf * cS[u] + gi * tanh_(gc);
            cS[u] = cn;
            tcS[u] = tanh_(cn);
        }
        __syncthreads();

        if (tid < 96) {
            int j = tid >> 5, o = (tid & 31) * 4;
            float4 a0 = *(float4*)&part2[tid][0];
            float4 a1 = *(float4*)&part2[tid + 96][0];
            float4 r;
            r.x = fmaxf(a0.x + a1.x + DbL[j][o], 0.f);
            r.y = fmaxf(a0.y + a1.y + DbL[j][o + 1], 0.f);
            r.z = fmaxf(a0.z + a1.z + DbL[j][o + 2], 0.f);
            r.w = fmaxf(a0.w + a1.w + DbL[j][o + 3], 0.f);
            *(float4*)&pS[4 * tid] = r;
        }
        __syncthreads();

        if (tid < 256) {
            int q = tid & 31, ks = tid >> 5;
            float4 acc = {0.f, 0.f, 0.f, 0.f};
            dotq<WS>(wAw, q, 32, pS, ks * 48, 48, acc);
            *(float4*)&part3[tid][0] = acc;
        } else if (tid < 384) {
            int e = tid - 256;
#pragma unroll
            for (int j = 0; j < 3; ++j) {
                int q = j * 128 + e;
                sS[q] = stkj[j][0][e] * pS[q] + stkj[j][1][e] * sS[q];
            }
        }
        __syncthreads();

        if (tid < 128) {
            int u = tid;
            float y = AbL[u];
#pragma unroll
            for (int ks = 0; ks < 8; ++ks) y += part3[ks * 32 + (u >> 2)][u & 3];
            float hn = sigf(y) * tcS[u];
            hS[u] = hn;
            outp[((size_t)bp * TT + t) * 128 + u] = hn;
        }
        __syncthreads();
    }
}

extern "C" void kernel_launch(void* const* d_in, const int* in_sizes, int n_in,
                              void* d_out, int out_size, void* d_ws, size_t ws_size,
                              hipStream_t stream) {
    const float* x    = (const float*)d_in[0];
    const float* Wk   = (const float*)d_in[1];
    const float* Wr   = (const float*)d_in[2];
    const float* bias = (const float*)d_in[3];
    const float* Wx   = (const float*)d_in[4];
    const float* Wh   = (const float*)d_in[5];
    const float* stk  = (const float*)d_in[6];
    const float* Dw   = (const float*)d_in[7];
    const float* Db   = (const float*)d_in[8];
    const float* Aw   = (const float*)d_in[9];
    const float* Ab   = (const float*)d_in[10];
    float* outp = (float*)d_out;

    const size_t needNew = (size_t)2 * BB * TT * 384 * sizeof(__half);  // 201,326,592
    const size_t needW   = 196608 * sizeof(__half);                     // fp16 weights
    if (ws_size >= needNew) {
        uint2* gxb = (uint2*)d_ws;
        uint2* axb = gxb + (size_t)BB * TT * 96;
        gax_pre2<<<dim3(BB, 64), dim3(384), 0, stream>>>(x, Wk, Wx, gxb, axb);
        subrec5<<<dim3(BB, 3), dim3(512), 0, stream>>>(Wh, Dw, stk, Db, axb);
        aggmm<<<dim3(BB, 16), dim3(256), 0, stream>>>(Aw, Ab, axb);
        gaterec4<<<dim3(BB), dim3(512), 0, stream>>>(Wr, bias, gxb, axb, outp);
    } else if (ws_size >= needW) {
        __half* wt = (__half*)d_ws;
        convert_w<<<dim3(384), dim3(512), 0, stream>>>(Wr, Wh, Dw, Aw, wt);
        tkan<true><<<dim3(BB), dim3(512), 0, stream>>>(
            x, Wk, Wr, bias, Wx, Wh, stk, Dw, Db, Aw, Ab, wt, outp);
    } else {
        tkan<false><<<dim3(BB), dim3(512), 0, stream>>>(
            x, Wk, Wr, bias, Wx, Wh, stk, Dw, Db, Aw, Ab, (const __half*)nullptr,
            outp);
    }
}